// Round 12
// baseline (266.566 us; speedup 1.0000x reference)
//
#include <hip/hip_runtime.h>

// VQ-VAE VectorQuantizer forward for MI355X (gfx950) — barrier-free MFMA argmin.
// z_e: (64, 256, 32, 32) fp32; codebook: (512, 256) fp32.
// Outputs concatenated in d_out (float32):
//   [0, 16777216)        z_q_st  (== z_e + (z_q - z_e), fp32 elementwise)
//   [16777216]           commitment_loss
//   [16777217]           codebook_loss (same value)
//   [16777218, +65536)   indices (as float)
//
// Index semantics: bitwise emulation of numpy-fp32
//   d = sum(z**2,axis=1,keepdims=True) + sum(e**2,axis=1) - 2*matmul(z, e.T)
//   idx = argmin(d, axis=1)   (first occurrence on exact fp32 ties)
//
// ROUND-11 POST-MORTEM: the 4-wave barrier-convoy block issued nothing 75%
// of cycles (2K MFMA + 4.6K VALU of 29K cy/block). Root cause: 19 barriers
// per block x only 2 independent barrier-groups per CU. THIS VERSION:
// one fully independent wave per 32 rows (no LDS, no __syncthreads in the
// argmin kernel). Filter: per-lane sorted top-4 of s~ = B - 2*M~ (A dropped:
// rank-invariant per row; EPS bound 4e-4 << EPS=1.5e-3). ~87% rows resolve
// in-wave (total==1); rest go to a pending list (<=3 codes in a u64, else
// full-scan flag) resolved by vq_exact2 with the bitwise numpy fp32 chain.

typedef __attribute__((ext_vector_type(8))) short short8v;
typedef __attribute__((ext_vector_type(4))) float float4v;
typedef unsigned short ushort_t;
typedef unsigned long long u64;

namespace {
constexpr int K = 512;
constexpr int D = 256;
constexpr int HW = 1024;          // 32*32
constexpr int NROWS = 65536;      // 64*HW
constexpr int CHW = D * HW;       // 262144

constexpr int ZQ_SIZE = 64 * CHW; // 16777216
constexpr int LOSS0_OFF = ZQ_SIZE;
constexpr int LOSS1_OFF = ZQ_SIZE + 1;
constexpr int IDX_OFF = ZQ_SIZE + 2;

// workspace layout (float offsets), ~1.03 MB total
// ehb: frag-blocked bf16 codebook: for code-tile t (16 codes), k-step s
// (32 d), lane = kg*16+l15: ehb[((t*8+s)*64 + lane)*8 + j] =
//   bf16(cb[t*16+l15][s*32+kg*8+j])  -> one dwordx4 per lane per (t,s).
constexpr int WS_EH_FLOATS = (K * D) / 2;   // 65536 floats
constexpr int WS_B = WS_EH_FLOATS;          // ||e_k||^2 exact, 512
constexpr int WS_KIDX = WS_B + K;           // best index per row, 65536
constexpr int WS_PART = WS_KIDX + NROWS;    // loss partials, 2048
constexpr int WS_PCNT = WS_PART + 2048;     // pending counter, 4
constexpr int WS_PMETA = WS_PCNT + 4;       // u64 per pending row, 2*65536 fl

constexpr int NBLK_A = NROWS / 128;         // 512 blocks x 4 indep waves
constexpr int NBLK_G = 2048;
constexpr int NBLK_E = 512;                 // exact: 2048 waves grid-strided

constexpr float EPS_CAND = 1.5e-3f;         // >= 4x the |s~-s| bound
}  // namespace

__device__ __forceinline__ ushort_t bf16_rne(float f) {
    unsigned u = __float_as_uint(f);
    u += 0x7fffu + ((u >> 16) & 1u);   // RNE (no NaN in data)
    return (ushort_t)(u >> 16);
}

// sorted top-4 smallest insert; all indices static after inlining+unroll.
__device__ __forceinline__ void ins4(float& mn, float* sc, int* cd,
                                     float s, int k) {
    mn = fminf(mn, s);
    if (s < sc[3]) { sc[3] = s; cd[3] = k; }
    if (sc[3] < sc[2]) { float tf = sc[2]; sc[2] = sc[3]; sc[3] = tf;
                         int ti = cd[2]; cd[2] = cd[3]; cd[3] = ti; }
    if (sc[2] < sc[1]) { float tf = sc[1]; sc[1] = sc[2]; sc[2] = tf;
                         int ti = cd[1]; cd[1] = cd[2]; cd[2] = ti; }
    if (sc[1] < sc[0]) { float tf = sc[0]; sc[0] = sc[1]; sc[1] = tf;
                         int ti = cd[0]; cd[0] = cd[1]; cd[1] = ti; }
}

// ---------------------------------------------------------------------------
// Kernel 1: frag-blocked bf16 codebook + exact numpy-pairwise ||e_k||^2;
// zeroes the pending counter.
__global__ void vq_prep(const float* __restrict__ cb, float* __restrict__ ws) {
    const int k = blockIdx.x;
    const int t = threadIdx.x;  // == d
    if (k == 0 && t == 0) reinterpret_cast<int*>(ws + WS_PCNT)[0] = 0;
    ushort_t* ehb = (ushort_t*)ws;
    {
        const int tt = k >> 4, l15 = k & 15;
        const int s = t >> 5, kg = (t >> 3) & 3, j = t & 7;
        ehb[(size_t)(((tt * 8 + s) * 64) + kg * 16 + l15) * 8 + j] =
            bf16_rne(cb[k * D + t]);
    }
    __shared__ float r16[16];
    if (t < 16) {
#pragma clang fp contract(off)
        const float* x = cb + k * D + (t >> 3) * 128;
        const int j = t & 7;
        float v = x[j];
        float r = v * v;
        for (int i = 1; i < 16; ++i) {
            float w = x[8 * i + j];
            r += w * w;
        }
        r16[t] = r;
    }
    __syncthreads();
    if (t == 0) {
#pragma clang fp contract(off)
        float lo = ((r16[0] + r16[1]) + (r16[2] + r16[3])) +
                   ((r16[4] + r16[5]) + (r16[6] + r16[7]));
        float hi = ((r16[8] + r16[9]) + (r16[10] + r16[11])) +
                   ((r16[12] + r16[13]) + (r16[14] + r16[15]));
        ws[WS_B + k] = lo + hi;
    }
}

// ---------------------------------------------------------------------------
// Kernel 2: barrier-free argmin. One wave = 32 rows, all in registers.
__global__ __launch_bounds__(256, 3) void vq_argmin6(
    const float* __restrict__ z_e, const ushort_t* __restrict__ ehb,
    const float* __restrict__ Bv, int* __restrict__ gpcnt,
    u64* __restrict__ pmeta, int* __restrict__ wsidx,
    float* __restrict__ out) {
    const int lane = threadIdx.x & 63;
    const int wid = blockIdx.x * 4 + (threadIdx.x >> 6);
    const int row0 = wid * 32;
    const int b = row0 >> 10;
    const int hw0 = row0 & 1023;
    const int l15 = lane & 15;
    const int kg = lane >> 4;

    // ---- z b-frags: zfr[rt][s][j] = bf16(z[d=s*32+kg*8+j][hw0+rt*16+l15])
    short8v zfr[2][8];
    {
        const float* zb0 = z_e + (size_t)b * CHW + hw0 + l15;
        const float* zb1 = zb0 + 16;
#pragma unroll
        for (int s = 0; s < 8; ++s) {
            float f0[8], f1[8];
#pragma unroll
            for (int j = 0; j < 8; ++j) {
                const size_t off = (size_t)(s * 32 + kg * 8 + j) * HW;
                f0[j] = zb0[off];
                f1[j] = zb1[off];
            }
            short8v v0, v1;
#pragma unroll
            for (int j = 0; j < 8; ++j) {
                v0[j] = (short)bf16_rne(f0[j]);
                v1[j] = (short)bf16_rne(f1[j]);
            }
            zfr[0][s] = v0;
            zfr[1][s] = v1;
        }
    }

    // ---- per-row filter state (2 rows per lane: l15 and 16+l15)
    float mn[2] = {3.0e38f, 3.0e38f};
    float sc[2][4];
    int cd[2][4];
#pragma unroll
    for (int rt = 0; rt < 2; ++rt)
#pragma unroll
        for (int i = 0; i < 4; ++i) { sc[rt][i] = 3.0e38f; cd[rt][i] = 0x7fffffff; }

    // ---- main loop over 32 code-tiles; e A-frags stream from L2.
    const ushort_t* ap = ehb + lane * 8;
#pragma unroll 2
    for (int t = 0; t < 32; ++t) {
        float4v a0 = {0.f, 0.f, 0.f, 0.f};
        float4v a1 = {0.f, 0.f, 0.f, 0.f};
#pragma unroll
        for (int s = 0; s < 8; ++s) {
            const short8v a =
                *reinterpret_cast<const short8v*>(ap + (size_t)(t * 8 + s) * 512);
            a0 = __builtin_amdgcn_mfma_f32_16x16x32_bf16(a, zfr[0][s], a0, 0, 0, 0);
            a1 = __builtin_amdgcn_mfma_f32_16x16x32_bf16(a, zfr[1][s], a1, 0, 0, 0);
        }
#pragma unroll
        for (int r = 0; r < 4; ++r) {
            const int code = t * 16 + 4 * kg + r;
            const float Bk = Bv[code];
            ins4(mn[0], sc[0], cd[0], Bk - 2.0f * a0[r], code);
            ins4(mn[1], sc[1], cd[1], Bk - 2.0f * a1[r], code);
        }
    }

    // ---- per-row resolution, rt = 0 then 1 (rows l15, 16+l15)
#pragma unroll
    for (int rt = 0; rt < 2; ++rt) {
        float g = mn[rt];
        g = fminf(g, __shfl_xor(g, 16));
        g = fminf(g, __shfl_xor(g, 32));
        const float thr = g + EPS_CAND;
        int cnt = (sc[rt][0] <= thr) + (sc[rt][1] <= thr) +
                  (sc[rt][2] <= thr) + (sc[rt][3] <= thr);
        int total = cnt;
        total += __shfl_xor(total, 16);
        total += __shfl_xor(total, 32);
        int ovf = (cnt == 4) ? 1 : 0;   // all slots in-window -> maybe dropped one
        ovf |= __shfl_xor(ovf, 16);
        ovf |= __shfl_xor(ovf, 32);
        int wc = (cnt >= 1) ? cd[rt][0] : 0x7fffffff;
        wc = min(wc, __shfl_xor(wc, 16));
        wc = min(wc, __shfl_xor(wc, 32));
        const int row = row0 + rt * 16 + l15;
        const bool pend = (total != 1) || ovf;
        if (!pend && lane < 16) {
            wsidx[row] = wc;
            out[IDX_OFF + row] = (float)wc;
        }
        const u64 mask = __ballot(pend && lane < 16);
        if (mask != 0ull) {
            // pack this lane's in-window codes (sorted => prefix of slots)
            unsigned w0 =
                ((cnt >= 1) ? (unsigned)cd[rt][0] : 0xFFFFu) |
                (((cnt >= 2) ? (unsigned)cd[rt][1] : 0xFFFFu) << 16);
            unsigned w1 =
                ((cnt >= 3) ? (unsigned)cd[rt][2] : 0xFFFFu) |
                (((cnt >= 4) ? (unsigned)cd[rt][3] : 0xFFFFu) << 16);
            unsigned gw0[4], gw1[4];
#pragma unroll
            for (int q = 0; q < 4; ++q) {
                gw0[q] = __shfl(w0, q * 16 + l15);
                gw1[q] = __shfl(w1, q * 16 + l15);
            }
            const int leader = __ffsll(mask) - 1;
            int base = 0;
            if (lane == leader) base = atomicAdd(gpcnt, __popcll(mask));
            base = __shfl(base, leader);
            if (pend && lane < 16) {
                const int slot =
                    base + __popcll(mask & ((1ull << lane) - 1ull));
                // first-3 in-window codes (static cndmask chain), else full
                unsigned c0 = 1023u, c1 = 1023u, c2 = 1023u;
                int n = 0;
#pragma unroll
                for (int q = 0; q < 4; ++q)
#pragma unroll
                    for (int h = 0; h < 4; ++h) {
                        const unsigned v =
                            (h < 2) ? ((gw0[q] >> (h * 16)) & 0xFFFFu)
                                    : ((gw1[q] >> ((h - 2) * 16)) & 0xFFFFu);
                        const bool val = (v != 0xFFFFu);
                        c2 = (val && n == 2) ? v : c2;
                        c1 = (val && n == 1) ? v : c1;
                        c0 = (val && n == 0) ? v : c0;
                        n += val ? 1 : 0;
                    }
                const bool full = ovf || (n > 3);
                pmeta[slot] = (u64)row | ((u64)(full ? 1 : 0) << 16) |
                              ((u64)c0 << 17) | ((u64)c1 << 27) |
                              ((u64)c2 << 37);
            }
        }
    }
}

// ---------------------------------------------------------------------------
// Kernel 3: exact re-score of pending rows. Wave per row, grid-strided.
// Stages the fp32 z row to per-wave LDS, computes the bitwise numpy pairwise
// A and the exact sequential fp32 chain per candidate; (d asc, k asc) reduce.
__global__ __launch_bounds__(256) void vq_exact2(
    const float* __restrict__ z_e, const float* __restrict__ cb,
    const float* __restrict__ Bv, const u64* __restrict__ pmeta,
    const int* __restrict__ gpcnt, int* __restrict__ wsidx,
    float* __restrict__ out) {
    __shared__ float zx[4][260];
    const int t = threadIdx.x;
    const int wv = t >> 6;
    const int lane = t & 63;
    const int nw = gridDim.x * 4;
    const int total = *gpcnt;

    for (int slot = blockIdx.x * 4 + wv; slot < total; slot += nw) {
        const u64 m = pmeta[slot];
        const int row = (int)(m & 0xFFFFu);
        const bool full = ((m >> 16) & 1ull) != 0;
        const unsigned c0 = (unsigned)((m >> 17) & 1023u);
        const unsigned c1 = (unsigned)((m >> 27) & 1023u);
        const unsigned c2 = (unsigned)((m >> 37) & 1023u);
        const int b = row >> 10;
        const int hw = row & 1023;
        const float* zp = z_e + (size_t)b * CHW + hw;
#pragma unroll
        for (int i = 0; i < 4; ++i)
            zx[wv][lane + 64 * i] = zp[(size_t)(lane + 64 * i) * HW];
        asm volatile("" ::: "memory");  // keep ds_writes before ds_reads

        // A = ||z_row||^2, exact numpy pairwise (16 chains on lanes 0..15,
        // tree computed redundantly on all lanes -> identical bits).
        float ch;
        {
#pragma clang fp contract(off)
            const int half = lane >> 3;
            const int j0 = lane & 7;
            const float* x = &zx[wv][half * 128];
            float v = x[j0];
            ch = v * v;
            for (int i = 1; i < 16; ++i) {
                float u = x[8 * i + j0];
                ch += u * u;
            }
        }
        float aval;
        {
#pragma clang fp contract(off)
            float r0 = __shfl(ch, 0), r1 = __shfl(ch, 1), r2 = __shfl(ch, 2),
                  r3 = __shfl(ch, 3), r4 = __shfl(ch, 4), r5 = __shfl(ch, 5),
                  r6 = __shfl(ch, 6), r7 = __shfl(ch, 7), r8 = __shfl(ch, 8),
                  r9 = __shfl(ch, 9), ra = __shfl(ch, 10), rb = __shfl(ch, 11),
                  rc = __shfl(ch, 12), rd = __shfl(ch, 13), re = __shfl(ch, 14),
                  rf = __shfl(ch, 15);
            float lo = ((r0 + r1) + (r2 + r3)) + ((r4 + r5) + (r6 + r7));
            float hi = ((r8 + r9) + (ra + rb)) + ((rc + rd) + (re + rf));
            aval = lo + hi;
        }

        float bd = 3.0e38f;
        int bk = 0x7fffffff;
        if (full) {
            for (int i = 0; i < 8; ++i) {
                const int k = lane + 64 * i;
                const float* ep = cb + (size_t)k * D;
                float a = 0.f;
#pragma unroll 8
                for (int c = 0; c < D; ++c) a = fmaf(zx[wv][c], ep[c], a);
                float dv;
                {
#pragma clang fp contract(off)
                    float t1 = aval + Bv[k];
                    dv = t1 - 2.0f * a;
                }
                if (dv < bd || (dv == bd && k < bk)) { bd = dv; bk = k; }
            }
        } else {
            const unsigned myk = (lane == 0) ? c0 : (lane == 1) ? c1 : c2;
            if (lane < 3 && myk < 512u) {
                const int k = (int)myk;
                const float* ep = cb + (size_t)k * D;
                float a = 0.f;
#pragma unroll 8
                for (int c = 0; c < D; ++c) a = fmaf(zx[wv][c], ep[c], a);
                float dv;
                {
#pragma clang fp contract(off)
                    float t1 = aval + Bv[k];
                    dv = t1 - 2.0f * a;
                }
                bd = dv;
                bk = k;
            }
        }
#pragma unroll
        for (int s = 1; s < 64; s <<= 1) {
            float od = __shfl_xor(bd, s);
            int ok = __shfl_xor(bk, s);
            if (od < bd || (od == bd && ok < bk)) { bd = od; bk = ok; }
        }
        if (lane == 0) {
            wsidx[row] = bk;
            out[IDX_OFF + row] = (float)bk;
        }
    }
}

// ---------------------------------------------------------------------------
// Kernel 4: streaming gather / straight-through write / loss partials.
__global__ __launch_bounds__(256, 8) void vq_gather2(
    const float* __restrict__ z_e, const float* __restrict__ cb,
    const int* __restrict__ wsidx, float* __restrict__ part,
    float* __restrict__ out) {
    __shared__ float wpart[4];
    const int t = threadIdx.x;
    const int blk = blockIdx.x;
    const int cg = blk & 7;
    const int q = (blk >> 3) & 3;
    const int b = blk >> 5;
    const int lane = t & 63;
    const int csub = t >> 6;
    const int hw = q * 256 + lane * 4;

    const int4 kk = *reinterpret_cast<const int4*>(&wsidx[b * HW + hw]);
    const float* e0 = cb + (size_t)kk.x * D;
    const float* e1 = cb + (size_t)kk.y * D;
    const float* e2 = cb + (size_t)kk.z * D;
    const float* e3 = cb + (size_t)kk.w * D;
    const size_t zoff = (size_t)b * CHW + hw;

    float accum = 0.f;
#pragma unroll 2
    for (int i = 0; i < 8; ++i) {
        const int c = cg * 32 + csub * 8 + i;
        const size_t off = zoff + (size_t)c * HW;
        const float4 z4 = *reinterpret_cast<const float4*>(&z_e[off]);
        const float ex = e0[c], ey = e1[c], ez = e2[c], ew = e3[c];
        float4 o4;
        o4.x = z4.x + (ex - z4.x);
        o4.y = z4.y + (ey - z4.y);
        o4.z = z4.z + (ez - z4.z);
        o4.w = z4.w + (ew - z4.w);
        *reinterpret_cast<float4*>(&out[off]) = o4;
        accum = fmaf(z4.x - ex, z4.x - ex, accum);
        accum = fmaf(z4.y - ey, z4.y - ey, accum);
        accum = fmaf(z4.z - ez, z4.z - ez, accum);
        accum = fmaf(z4.w - ew, z4.w - ew, accum);
    }
#pragma unroll
    for (int s = 1; s < 64; s <<= 1) accum += __shfl_xor(accum, s);
    if (lane == 0) wpart[csub] = accum;
    __syncthreads();
    if (t == 0) part[blk] = (wpart[0] + wpart[1]) + (wpart[2] + wpart[3]);
}

// ---------------------------------------------------------------------------
// Kernel 5: final loss reduction (2048 partials, fp64, deterministic).
__global__ void vq_finish(const float* __restrict__ part, float* __restrict__ out) {
    const int t = threadIdx.x;
    double s = 0.0;
#pragma unroll
    for (int i = 0; i < 8; ++i) s += (double)part[t + 256 * i];
#pragma unroll
    for (int m = 1; m < 64; m <<= 1) s += __shfl_xor(s, m);
    __shared__ double wsum[4];
    if ((t & 63) == 0) wsum[t >> 6] = s;
    __syncthreads();
    if (t == 0) {
        double mean = (wsum[0] + wsum[1] + wsum[2] + wsum[3]) / (double)ZQ_SIZE;
        out[LOSS0_OFF] = (float)mean;
        out[LOSS1_OFF] = (float)mean;
    }
}

// ---------------------------------------------------------------------------
extern "C" void kernel_launch(void* const* d_in, const int* in_sizes, int n_in,
                              void* d_out, int out_size, void* d_ws, size_t ws_size,
                              hipStream_t stream) {
    const float* z_e = (const float*)d_in[0];
    const float* cb = (const float*)d_in[1];
    float* out = (float*)d_out;
    float* ws = (float*)d_ws;

    const ushort_t* ehb = (const ushort_t*)ws;
    float* Bv = ws + WS_B;
    int* wsidx = (int*)(ws + WS_KIDX);
    float* part = ws + WS_PART;
    int* gpcnt = (int*)(ws + WS_PCNT);
    u64* pmeta = (u64*)(ws + WS_PMETA);

    vq_prep<<<K, D, 0, stream>>>(cb, ws);
    vq_argmin6<<<NBLK_A, 256, 0, stream>>>(z_e, ehb, Bv, gpcnt, pmeta, wsidx, out);
    vq_exact2<<<NBLK_E, 256, 0, stream>>>(z_e, cb, Bv, pmeta, gpcnt, wsidx, out);
    vq_gather2<<<NBLK_G, 256, 0, stream>>>(z_e, cb, wsidx, part, out);
    vq_finish<<<1, 256, 0, stream>>>(part, out);
}

// Round 16
// 223.984 us; speedup vs baseline: 1.1901x; 1.1901x over previous
//
#include <hip/hip_runtime.h>

// VQ-VAE VectorQuantizer forward for MI355X (gfx950) — barrier-free MFMA argmin
// with a wave-private 16-slot global_load_lds ring (counted vmcnt, WAR-free).
// z_e: (64, 256, 32, 32) fp32; codebook: (512, 256) fp32.
// Outputs concatenated in d_out (float32):
//   [0, 16777216)        z_q_st ; [16777216] commit loss ; [+1] codebook loss
//   [16777218, +65536)   indices (as float)
//
// Index semantics: bitwise emulation of numpy-fp32
//   d = ||z||^2 + ||e||^2 - 2*matmul(z, e.T); idx = argmin (first occurrence).
// bf16(hi) MFMA filter (EPS window) -> rare rows re-scored with the exact
// sequential fp32 chain (ascending d) in vq_exact3.
//
// ROUND-15 POST-MORTEM (correctness): the 8-slot ring refilled the SAME slot
// it had just read ("read samples LDS before DMA lands" was an issue-time
// argument, not a completion guarantee). Under LDS congestion (12 one-wave
// blocks/CU), a queued ds_read can execute AFTER the refill lands -> reads
// step i+8 instead of i -> wrong candidates. FIX: 16-slot ring; read slot
// i&15, refill slot (i+8)&15 — a slot whose read completed >=8 iterations
// ago (lgkm wait before that step's MFMA proves completion). vmcnt counting
// unchanged: 8 refills in flight, vmcnt(7) certifies the slot being read.

typedef __attribute__((ext_vector_type(8))) short short8v;
typedef __attribute__((ext_vector_type(4))) float float4v;
typedef unsigned short ushort_t;
typedef unsigned long long u64;

#define GLOAD_LDS16(gsrc, ldst)                                                \
    __builtin_amdgcn_global_load_lds(                                          \
        (const __attribute__((address_space(1))) unsigned*)(gsrc),             \
        (__attribute__((address_space(3))) unsigned*)(ldst), 16, 0, 0)

namespace {
constexpr int K = 512;
constexpr int D = 256;
constexpr int HW = 1024;
constexpr int NROWS = 65536;
constexpr int CHW = D * HW;

constexpr int ZQ_SIZE = 64 * CHW;
constexpr int LOSS0_OFF = ZQ_SIZE;
constexpr int LOSS1_OFF = ZQ_SIZE + 1;
constexpr int IDX_OFF = ZQ_SIZE + 2;

// workspace layout (float offsets)
// ehb: frag-blocked bf16 codebook: step n = t*8+s (tile t: 16 codes, s: 32 d),
// lane = kg*16+l15: ehb[(n*64 + lane)*8 + j] = bf16(cb[t*16+l15][s*32+kg*8+j])
constexpr int WS_EH_FLOATS = (K * D) / 2;
constexpr int WS_B = WS_EH_FLOATS;          // ||e_k||^2 exact, 512
constexpr int WS_KIDX = WS_B + K;           // best index per row, 65536
constexpr int WS_PART = WS_KIDX + NROWS;    // loss partials, 2048
constexpr int WS_PCNT = WS_PART + 2048;     // pending counter, 4
constexpr int WS_PMETA = WS_PCNT + 4;       // u64 per pending row

constexpr int NBLK_A = NROWS / 32;          // 2048 blocks x 1 wave x 32 rows
constexpr int NBLK_G = 2048;
constexpr int NBLK_E = 1024;                // exact: 4096 waves grid-strided

constexpr float EPS_CAND = 1.5e-3f;
}  // namespace

__device__ __forceinline__ ushort_t bf16_rne(float f) {
    unsigned u = __float_as_uint(f);
    u += 0x7fffu + ((u >> 16) & 1u);
    return (ushort_t)(u >> 16);
}

__device__ __forceinline__ void ins4(float* sc, int* cd, float s, int k) {
    if (s < sc[3]) { sc[3] = s; cd[3] = k; }
    if (sc[3] < sc[2]) { float tf = sc[2]; sc[2] = sc[3]; sc[3] = tf;
                         int ti = cd[2]; cd[2] = cd[3]; cd[3] = ti; }
    if (sc[2] < sc[1]) { float tf = sc[1]; sc[1] = sc[2]; sc[2] = tf;
                         int ti = cd[1]; cd[1] = cd[2]; cd[2] = ti; }
    if (sc[1] < sc[0]) { float tf = sc[0]; sc[0] = sc[1]; sc[1] = tf;
                         int ti = cd[0]; cd[0] = cd[1]; cd[1] = ti; }
}

// ---------------------------------------------------------------------------
// Kernel 1: frag-blocked bf16 codebook + exact numpy-pairwise ||e_k||^2;
// zeroes the pending counter.
__global__ void vq_prep(const float* __restrict__ cb, float* __restrict__ ws) {
    const int k = blockIdx.x;
    const int t = threadIdx.x;  // == d
    if (k == 0 && t == 0) reinterpret_cast<int*>(ws + WS_PCNT)[0] = 0;
    ushort_t* ehb = (ushort_t*)ws;
    {
        const int tt = k >> 4, l15 = k & 15;
        const int s = t >> 5, kg = (t >> 3) & 3, j = t & 7;
        ehb[(size_t)(((tt * 8 + s) * 64) + kg * 16 + l15) * 8 + j] =
            bf16_rne(cb[k * D + t]);
    }
    __shared__ float r16[16];
    if (t < 16) {
#pragma clang fp contract(off)
        const float* x = cb + k * D + (t >> 3) * 128;
        const int j = t & 7;
        float v = x[j];
        float r = v * v;
        for (int i = 1; i < 16; ++i) {
            float w = x[8 * i + j];
            r += w * w;
        }
        r16[t] = r;
    }
    __syncthreads();
    if (t == 0) {
#pragma clang fp contract(off)
        float lo = ((r16[0] + r16[1]) + (r16[2] + r16[3])) +
                   ((r16[4] + r16[5]) + (r16[6] + r16[7]));
        float hi = ((r16[8] + r16[9]) + (r16[10] + r16[11])) +
                   ((r16[12] + r16[13]) + (r16[14] + r16[15]));
        ws[WS_B + k] = lo + hi;
    }
}

// ---------------------------------------------------------------------------
// Kernel 2: argmin. ONE wave per block (64 threads), 32 rows, zero barriers.
// a-frags stream via a 16-slot wave-private global_load_lds ring: read slot
// i&15, refill slot (i+8)&15 (read-complete >=8 iters ago -> no WAR race);
// s_waitcnt vmcnt(7) certifies the slot being read. No other vmcnt ops in
// the loop (Bv pre-staged to LDS; z loads drained before the loop).
__global__ __launch_bounds__(64, 3) void vq_argmin7(
    const float* __restrict__ z_e, const ushort_t* __restrict__ ehb,
    const float* __restrict__ Bv, int* __restrict__ gpcnt,
    u64* __restrict__ pmeta, int* __restrict__ wsidx,
    float* __restrict__ out) {
    __shared__ __align__(16) char ring[16 * 1024];  // 16 slots x 1KB
    __shared__ float lds_B[K];                      // 2 KB

    const int lane = threadIdx.x;
    const int wid = blockIdx.x;
    const int row0 = wid * 32;
    const int b = row0 >> 10;
    const int hw0 = row0 & 1023;
    const int l15 = lane & 15;
    const int kg = lane >> 4;

    // ---- prologue DMA: steps 0..7 into slots 0..7 (global src per-lane;
    // LDS dst = wave-uniform base, HW scatters lane*16).
    const char* gA = (const char*)ehb + (size_t)lane * 16;
#pragma unroll
    for (int n = 0; n < 8; ++n)
        GLOAD_LDS16(gA + (size_t)n * 1024, ring + n * 1024);

    // ---- stage Bv -> LDS (own wave; same-wave DS ordering via lgkmcnt)
    {
        const float4* b4 = reinterpret_cast<const float4*>(Bv);
        float4* l4 = reinterpret_cast<float4*>(lds_B);
        l4[lane] = b4[lane];
        l4[lane + 64] = b4[lane + 64];
    }

    // ---- z b-frags (fp32 strided loads -> bf16 RNE), overlaps DMA flight
    short8v zfr0[8], zfr1[8];
    {
        const float* zb0 = z_e + (size_t)b * CHW + hw0 + l15;
        const float* zb1 = zb0 + 16;
#pragma unroll
        for (int s = 0; s < 8; ++s) {
            float f0[8], f1[8];
#pragma unroll
            for (int j = 0; j < 8; ++j) {
                const size_t off = (size_t)(s * 32 + kg * 8 + j) * HW;
                f0[j] = zb0[off];
                f1[j] = zb1[off];
            }
            short8v v0, v1;
#pragma unroll
            for (int j = 0; j < 8; ++j) {
                v0[j] = (short)bf16_rne(f0[j]);
                v1[j] = (short)bf16_rne(f1[j]);
            }
            zfr0[s] = v0;
            zfr1[s] = v1;
        }
    }

    // ---- per-row filter state (rows l15 and 16+l15)
    float sc[2][4];
    int cd[2][4];
#pragma unroll
    for (int rt = 0; rt < 2; ++rt)
#pragma unroll
        for (int i = 0; i < 4; ++i) { sc[rt][i] = 3.0e38f; cd[rt][i] = 0x7fffffff; }

    // ---- FULL DRAIN: prologue DMAs + all z loads have landed.
    asm volatile("s_waitcnt vmcnt(0)" ::: "memory");

    // ---- main loop: tiles 0..30 pipelined (iters 0..247), tile 31 drained.
#define TILE_EPILOGUE(T, A0, A1)                                               \
    {                                                                          \
        _Pragma("unroll") for (int r = 0; r < 4; ++r) {                        \
            const int code = (T) * 16 + 4 * kg + r;                            \
            const float Bk = lds_B[code];                                      \
            ins4(sc[0], cd[0], Bk - 2.0f * (A0)[r], code);                     \
            ins4(sc[1], cd[1], Bk - 2.0f * (A1)[r], code);                     \
        }                                                                      \
    }

    for (int t = 0; t < 31; ++t) {
        float4v a0 = {0.f, 0.f, 0.f, 0.f};
        float4v a1 = {0.f, 0.f, 0.f, 0.f};
#pragma unroll
        for (int s = 0; s < 8; ++s) {
            const int i = t * 8 + s;
            // <=8 refills in flight; oldest loaded step i into slot i&15.
            asm volatile("s_waitcnt vmcnt(7)" ::: "memory");
            const short8v a = *reinterpret_cast<const short8v*>(
                ring + (i & 15) * 1024 + lane * 16);
            a0 = __builtin_amdgcn_mfma_f32_16x16x32_bf16(a, zfr0[s], a0, 0, 0, 0);
            a1 = __builtin_amdgcn_mfma_f32_16x16x32_bf16(a, zfr1[s], a1, 0, 0, 0);
            // refill step i+8 into slot (i+8)&15 — 8 slots away from the one
            // just read; that slot's own read completed >=8 iterations ago.
            GLOAD_LDS16(gA + (size_t)(i + 8) * 1024, ring + ((i + 8) & 15) * 1024);
        }
        TILE_EPILOGUE(t, a0, a1);
    }
    {
        asm volatile("s_waitcnt vmcnt(0)" ::: "memory");
        float4v a0 = {0.f, 0.f, 0.f, 0.f};
        float4v a1 = {0.f, 0.f, 0.f, 0.f};
#pragma unroll
        for (int s = 0; s < 8; ++s) {
            const int i = 248 + s;  // slots 8..15, filled by iters 240..247
            const short8v a = *reinterpret_cast<const short8v*>(
                ring + (i & 15) * 1024 + lane * 16);
            a0 = __builtin_amdgcn_mfma_f32_16x16x32_bf16(a, zfr0[s], a0, 0, 0, 0);
            a1 = __builtin_amdgcn_mfma_f32_16x16x32_bf16(a, zfr1[s], a1, 0, 0, 0);
        }
        TILE_EPILOGUE(31, a0, a1);
    }
#undef TILE_EPILOGUE

    // ---- per-row resolution (identical logic to round 12's passing kernel)
#pragma unroll
    for (int rt = 0; rt < 2; ++rt) {
        float g = sc[rt][0];
        g = fminf(g, __shfl_xor(g, 16));
        g = fminf(g, __shfl_xor(g, 32));
        const float thr = g + EPS_CAND;
        int cnt = (sc[rt][0] <= thr) + (sc[rt][1] <= thr) +
                  (sc[rt][2] <= thr) + (sc[rt][3] <= thr);
        int total = cnt;
        total += __shfl_xor(total, 16);
        total += __shfl_xor(total, 32);
        int ovf = (cnt == 4) ? 1 : 0;
        ovf |= __shfl_xor(ovf, 16);
        ovf |= __shfl_xor(ovf, 32);
        int wc = (cnt >= 1) ? cd[rt][0] : 0x7fffffff;
        wc = min(wc, __shfl_xor(wc, 16));
        wc = min(wc, __shfl_xor(wc, 32));
        const int row = row0 + rt * 16 + l15;
        const bool pend = (total != 1) || ovf;
        if (!pend && lane < 16) {
            wsidx[row] = wc;
            out[IDX_OFF + row] = (float)wc;
        }
        const u64 mask = __ballot(pend && lane < 16);
        if (mask != 0ull) {
            unsigned w0 =
                ((cnt >= 1) ? (unsigned)cd[rt][0] : 0xFFFFu) |
                (((cnt >= 2) ? (unsigned)cd[rt][1] : 0xFFFFu) << 16);
            unsigned w1 =
                ((cnt >= 3) ? (unsigned)cd[rt][2] : 0xFFFFu) |
                (((cnt >= 4) ? (unsigned)cd[rt][3] : 0xFFFFu) << 16);
            unsigned gw0[4], gw1[4];
#pragma unroll
            for (int q = 0; q < 4; ++q) {
                gw0[q] = __shfl(w0, q * 16 + l15);
                gw1[q] = __shfl(w1, q * 16 + l15);
            }
            const int leader = __ffsll(mask) - 1;
            int base = 0;
            if (lane == leader) base = atomicAdd(gpcnt, __popcll(mask));
            base = __shfl(base, leader);
            if (pend && lane < 16) {
                const int slot = base + __popcll(mask & ((1ull << lane) - 1ull));
                unsigned c0 = 1023u, c1 = 1023u, c2 = 1023u;
                int n = 0;
#pragma unroll
                for (int q = 0; q < 4; ++q)
#pragma unroll
                    for (int h = 0; h < 4; ++h) {
                        const unsigned v =
                            (h < 2) ? ((gw0[q] >> (h * 16)) & 0xFFFFu)
                                    : ((gw1[q] >> ((h - 2) * 16)) & 0xFFFFu);
                        const bool val = (v != 0xFFFFu);
                        c2 = (val && n == 2) ? v : c2;
                        c1 = (val && n == 1) ? v : c1;
                        c0 = (val && n == 0) ? v : c0;
                        n += val ? 1 : 0;
                    }
                const bool full = ovf || (n > 3);
                pmeta[slot] = (u64)row | ((u64)(full ? 1 : 0) << 16) |
                              ((u64)c0 << 17) | ((u64)c1 << 27) |
                              ((u64)c2 << 37);
            }
        }
    }
}

// ---------------------------------------------------------------------------
// Kernel 3: exact re-score of pending rows. Wave per row, grid-strided.
// z row + candidate e-rows staged to LDS; chains run LDS-fed.
__global__ __launch_bounds__(256, 4) void vq_exact3(
    const float* __restrict__ z_e, const float* __restrict__ cb,
    const float* __restrict__ Bv, const u64* __restrict__ pmeta,
    const int* __restrict__ gpcnt, int* __restrict__ wsidx,
    float* __restrict__ out) {
    __shared__ float zx[4][260];
    __shared__ float el[4][3][256];
    const int t = threadIdx.x;
    const int wv = t >> 6;
    const int lane = t & 63;
    const int nw = gridDim.x * 4;
    const int total = *gpcnt;

    for (int slot = blockIdx.x * 4 + wv; slot < total; slot += nw) {
        const u64 m = pmeta[slot];
        const int row = (int)(m & 0xFFFFu);
        const bool full = ((m >> 16) & 1ull) != 0;
        const unsigned cc[3] = {(unsigned)((m >> 17) & 1023u),
                                (unsigned)((m >> 27) & 1023u),
                                (unsigned)((m >> 37) & 1023u)};
        const int b = row >> 10;
        const int hw = row & 1023;
        const float* zp = z_e + (size_t)b * CHW + hw;
#pragma unroll
        for (int i = 0; i < 4; ++i)
            zx[wv][lane + 64 * i] = zp[(size_t)(lane + 64 * i) * HW];

        const int nc = (cc[0] < 512u) + (cc[1] < 512u) + (cc[2] < 512u);
        if (!full) {
            for (int j = 0; j < nc; ++j) {
                const float4* ep4 =
                    reinterpret_cast<const float4*>(cb + (size_t)cc[j] * D);
                reinterpret_cast<float4*>(&el[wv][j][0])[lane] = ep4[lane];
            }
        }
        asm volatile("" ::: "memory");  // staging stores precede chain reads

        // A = ||z||^2, exact numpy pairwise (chains on lanes 0..15).
        float ch;
        {
#pragma clang fp contract(off)
            const int half = lane >> 3;
            const int j0 = lane & 7;
            const float* x = &zx[wv][half * 128];
            float v = x[j0];
            ch = v * v;
            for (int i = 1; i < 16; ++i) {
                float u = x[8 * i + j0];
                ch += u * u;
            }
        }
        float aval;
        {
#pragma clang fp contract(off)
            float r0 = __shfl(ch, 0), r1 = __shfl(ch, 1), r2 = __shfl(ch, 2),
                  r3 = __shfl(ch, 3), r4 = __shfl(ch, 4), r5 = __shfl(ch, 5),
                  r6 = __shfl(ch, 6), r7 = __shfl(ch, 7), r8 = __shfl(ch, 8),
                  r9 = __shfl(ch, 9), ra = __shfl(ch, 10), rb = __shfl(ch, 11),
                  rc = __shfl(ch, 12), rd = __shfl(ch, 13), re = __shfl(ch, 14),
                  rf = __shfl(ch, 15);
            float lo = ((r0 + r1) + (r2 + r3)) + ((r4 + r5) + (r6 + r7));
            float hi = ((r8 + r9) + (ra + rb)) + ((rc + rd) + (re + rf));
            aval = lo + hi;
        }

        float bd = 3.0e38f;
        int bk = 0x7fffffff;
        if (full) {
            for (int i = 0; i < 8; ++i) {
                const int k = lane + 64 * i;
                const float* ep = cb + (size_t)k * D;
                float a = 0.f;
#pragma unroll 8
                for (int c = 0; c < D; ++c) a = fmaf(zx[wv][c], ep[c], a);
                float dv;
                {
#pragma clang fp contract(off)
                    float t1 = aval + Bv[k];
                    dv = t1 - 2.0f * a;
                }
                if (dv < bd || (dv == bd && k < bk)) { bd = dv; bk = k; }
            }
        } else if (lane < nc) {
            const int k = (int)cc[lane];
            const float* ep = &el[wv][lane][0];
            float a = 0.f;
#pragma unroll 8
            for (int c = 0; c < D; ++c) a = fmaf(zx[wv][c], ep[c], a);
            {
#pragma clang fp contract(off)
                float t1 = aval + Bv[k];
                bd = t1 - 2.0f * a;
            }
            bk = k;
        }
#pragma unroll
        for (int s = 1; s < 64; s <<= 1) {
            float od = __shfl_xor(bd, s);
            int ok = __shfl_xor(bk, s);
            if (od < bd || (od == bd && ok < bk)) { bd = od; bk = ok; }
        }
        if (lane == 0) {
            wsidx[row] = bk;
            out[IDX_OFF + row] = (float)bk;
        }
    }
}

// ---------------------------------------------------------------------------
// Kernel 4: streaming gather / straight-through write / loss partials.
__global__ __launch_bounds__(256, 8) void vq_gather2(
    const float* __restrict__ z_e, const float* __restrict__ cb,
    const int* __restrict__ wsidx, float* __restrict__ part,
    float* __restrict__ out) {
    __shared__ float wpart[4];
    const int t = threadIdx.x;
    const int blk = blockIdx.x;
    const int cg = blk & 7;
    const int q = (blk >> 3) & 3;
    const int b = blk >> 5;
    const int lane = t & 63;
    const int csub = t >> 6;
    const int hw = q * 256 + lane * 4;

    const int4 kk = *reinterpret_cast<const int4*>(&wsidx[b * HW + hw]);
    const float* e0 = cb + (size_t)kk.x * D;
    const float* e1 = cb + (size_t)kk.y * D;
    const float* e2 = cb + (size_t)kk.z * D;
    const float* e3 = cb + (size_t)kk.w * D;
    const size_t zoff = (size_t)b * CHW + hw;

    float accum = 0.f;
#pragma unroll 2
    for (int i = 0; i < 8; ++i) {
        const int c = cg * 32 + csub * 8 + i;
        const size_t off = zoff + (size_t)c * HW;
        const float4 z4 = *reinterpret_cast<const float4*>(&z_e[off]);
        const float ex = e0[c], ey = e1[c], ez = e2[c], ew = e3[c];
        float4 o4;
        o4.x = z4.x + (ex - z4.x);
        o4.y = z4.y + (ey - z4.y);
        o4.z = z4.z + (ez - z4.z);
        o4.w = z4.w + (ew - z4.w);
        *reinterpret_cast<float4*>(&out[off]) = o4;
        accum = fmaf(z4.x - ex, z4.x - ex, accum);
        accum = fmaf(z4.y - ey, z4.y - ey, accum);
        accum = fmaf(z4.z - ez, z4.z - ez, accum);
        accum = fmaf(z4.w - ew, z4.w - ew, accum);
    }
#pragma unroll
    for (int s = 1; s < 64; s <<= 1) accum += __shfl_xor(accum, s);
    if (lane == 0) wpart[csub] = accum;
    __syncthreads();
    if (t == 0) part[blk] = (wpart[0] + wpart[1]) + (wpart[2] + wpart[3]);
}

// ---------------------------------------------------------------------------
// Kernel 5: final loss reduction (2048 partials, fp64, deterministic).
__global__ void vq_finish(const float* __restrict__ part, float* __restrict__ out) {
    const int t = threadIdx.x;
    double s = 0.0;
#pragma unroll
    for (int i = 0; i < 8; ++i) s += (double)part[t + 256 * i];
#pragma unroll
    for (int m = 1; m < 64; m <<= 1) s += __shfl_xor(s, m);
    __shared__ double wsum[4];
    if ((t & 63) == 0) wsum[t >> 6] = s;
    __syncthreads();
    if (t == 0) {
        double mean = (wsum[0] + wsum[1] + wsum[2] + wsum[3]) / (double)ZQ_SIZE;
        out[LOSS0_OFF] = (float)mean;
        out[LOSS1_OFF] = (float)mean;
    }
}

// ---------------------------------------------------------------------------
extern "C" void kernel_launch(void* const* d_in, const int* in_sizes, int n_in,
                              void* d_out, int out_size, void* d_ws, size_t ws_size,
                              hipStream_t stream) {
    const float* z_e = (const float*)d_in[0];
    const float* cb = (const float*)d_in[1];
    float* out = (float*)d_out;
    float* ws = (float*)d_ws;

    const ushort_t* ehb = (const ushort_t*)ws;
    float* Bv = ws + WS_B;
    int* wsidx = (int*)(ws + WS_KIDX);
    float* part = ws + WS_PART;
    int* gpcnt = (int*)(ws + WS_PCNT);
    u64* pmeta = (u64*)(ws + WS_PMETA);

    vq_prep<<<K, D, 0, stream>>>(cb, ws);
    vq_argmin7<<<NBLK_A, 64, 0, stream>>>(z_e, ehb, Bv, gpcnt, pmeta, wsidx, out);
    vq_exact3<<<NBLK_E, 256, 0, stream>>>(z_e, cb, Bv, pmeta, gpcnt, wsidx, out);
    vq_gather2<<<NBLK_G, 256, 0, stream>>>(z_e, cb, wsidx, part, out);
    vq_finish<<<1, 256, 0, stream>>>(part, out);
}

// Round 17
// 219.296 us; speedup vs baseline: 1.2156x; 1.0214x over previous
//
#include <hip/hip_runtime.h>

// VQ-VAE VectorQuantizer forward for MI355X (gfx950).
// Pipeline: prep -> argmin7 (barrier-free MFMA filter, 16-slot DMA ring,
// writes per-row pmeta) -> gather3 (z tile in LDS; resolves pending rows
// with the bitwise-exact numpy fp32 chain; gather/ST/loss; index output)
// -> finish.
// z_e: (64, 256, 32, 32) fp32; codebook: (512, 256) fp32.
// Outputs concatenated in d_out (float32):
//   [0, 16777216)        z_q_st ; [16777216] commit loss ; [+1] codebook loss
//   [16777218, +65536)   indices (as float)
//
// Index semantics: bitwise emulation of numpy-fp32
//   d = ||z||^2 + ||e||^2 - 2*matmul(z, e.T); idx = argmin (first occurrence).
//
// ROUND-16 POST-MORTEM: standalone vq_exact3 was the TOP dispatch (113us,
// VALUBusy 6%): each pending row re-fetched z as 256 scattered 64B lines +
// global-latency chains over ~4096 mostly-idle waves. FIX: exact resolution
// folded into the gather kernel where the full fp32 z tile is LDS-resident
// (coalesced DMA, read once). argmin7's ring loop (proven correct this
// round) is unchanged; its tail now writes one pmeta word per row
// (RESOLVED|k or full|c0|c1|c2) -- no global counter, no compaction.

typedef __attribute__((ext_vector_type(8))) short short8v;
typedef __attribute__((ext_vector_type(4))) float float4v;
typedef unsigned short ushort_t;
typedef unsigned long long u64;

#define GLOAD_LDS16(gsrc, ldst)                                                \
    __builtin_amdgcn_global_load_lds(                                          \
        (const __attribute__((address_space(1))) unsigned*)(gsrc),             \
        (__attribute__((address_space(3))) unsigned*)(ldst), 16, 0, 0)

namespace {
constexpr int K = 512;
constexpr int D = 256;
constexpr int HW = 1024;
constexpr int NROWS = 65536;
constexpr int CHW = D * HW;

constexpr int ZQ_SIZE = 64 * CHW;
constexpr int LOSS0_OFF = ZQ_SIZE;
constexpr int LOSS1_OFF = ZQ_SIZE + 1;
constexpr int IDX_OFF = ZQ_SIZE + 2;

// workspace layout (float offsets)
// ehb: frag-blocked bf16 codebook: step n = t*8+s (tile t: 16 codes, s: 32 d),
// lane = kg*16+l15: ehb[(n*64 + lane)*8 + j] = bf16(cb[t*16+l15][s*32+kg*8+j])
constexpr int WS_EH_FLOATS = (K * D) / 2;
constexpr int WS_B = WS_EH_FLOATS;          // ||e_k||^2 exact, 512
constexpr int WS_PART = WS_B + K;           // loss partials, 1024
constexpr int WS_PMETA = WS_PART + 1024;    // u64 per row, 2*65536 floats

constexpr int NBLK_A = NROWS / 32;          // 2048 blocks x 1 wave x 32 rows
constexpr int NBLK_G = NROWS / 64;          // 1024 gather blocks (64 rows)

constexpr float EPS_CAND = 1.5e-3f;
constexpr u64 RESOLVED = 1ull << 63;
}  // namespace

__device__ __forceinline__ ushort_t bf16_rne(float f) {
    unsigned u = __float_as_uint(f);
    u += 0x7fffu + ((u >> 16) & 1u);
    return (ushort_t)(u >> 16);
}

__device__ __forceinline__ void ins4(float* sc, int* cd, float s, int k) {
    if (s < sc[3]) { sc[3] = s; cd[3] = k; }
    if (sc[3] < sc[2]) { float tf = sc[2]; sc[2] = sc[3]; sc[3] = tf;
                         int ti = cd[2]; cd[2] = cd[3]; cd[3] = ti; }
    if (sc[2] < sc[1]) { float tf = sc[1]; sc[1] = sc[2]; sc[2] = tf;
                         int ti = cd[1]; cd[1] = cd[2]; cd[2] = ti; }
    if (sc[1] < sc[0]) { float tf = sc[0]; sc[0] = sc[1]; sc[1] = tf;
                         int ti = cd[0]; cd[0] = cd[1]; cd[1] = ti; }
}

// ---------------------------------------------------------------------------
// Kernel 1: frag-blocked bf16 codebook + exact numpy-pairwise ||e_k||^2.
__global__ void vq_prep(const float* __restrict__ cb, float* __restrict__ ws) {
    const int k = blockIdx.x;
    const int t = threadIdx.x;  // == d
    ushort_t* ehb = (ushort_t*)ws;
    {
        const int tt = k >> 4, l15 = k & 15;
        const int s = t >> 5, kg = (t >> 3) & 3, j = t & 7;
        ehb[(size_t)(((tt * 8 + s) * 64) + kg * 16 + l15) * 8 + j] =
            bf16_rne(cb[k * D + t]);
    }
    __shared__ float r16[16];
    if (t < 16) {
#pragma clang fp contract(off)
        const float* x = cb + k * D + (t >> 3) * 128;
        const int j = t & 7;
        float v = x[j];
        float r = v * v;
        for (int i = 1; i < 16; ++i) {
            float w = x[8 * i + j];
            r += w * w;
        }
        r16[t] = r;
    }
    __syncthreads();
    if (t == 0) {
#pragma clang fp contract(off)
        float lo = ((r16[0] + r16[1]) + (r16[2] + r16[3])) +
                   ((r16[4] + r16[5]) + (r16[6] + r16[7]));
        float hi = ((r16[8] + r16[9]) + (r16[10] + r16[11])) +
                   ((r16[12] + r16[13]) + (r16[14] + r16[15]));
        ws[WS_B + k] = lo + hi;
    }
}

// ---------------------------------------------------------------------------
// Kernel 2: argmin filter. ONE wave per block (64 threads), 32 rows, zero
// barriers. a-frags stream via a 16-slot wave-private global_load_lds ring:
// read slot i&15, refill slot (i+8)&15; s_waitcnt vmcnt(7) certifies the
// slot being read. Tail writes ONE pmeta word per row.
__global__ __launch_bounds__(64, 3) void vq_argmin7(
    const float* __restrict__ z_e, const ushort_t* __restrict__ ehb,
    const float* __restrict__ Bv, u64* __restrict__ pmeta) {
    __shared__ __align__(16) char ring[16 * 1024];  // 16 slots x 1KB
    __shared__ float lds_B[K];                      // 2 KB

    const int lane = threadIdx.x;
    const int wid = blockIdx.x;
    const int row0 = wid * 32;
    const int b = row0 >> 10;
    const int hw0 = row0 & 1023;
    const int l15 = lane & 15;
    const int kg = lane >> 4;

    // ---- prologue DMA: steps 0..7 into slots 0..7.
    const char* gA = (const char*)ehb + (size_t)lane * 16;
#pragma unroll
    for (int n = 0; n < 8; ++n)
        GLOAD_LDS16(gA + (size_t)n * 1024, ring + n * 1024);

    // ---- stage Bv -> LDS (own wave)
    {
        const float4* b4 = reinterpret_cast<const float4*>(Bv);
        float4* l4 = reinterpret_cast<float4*>(lds_B);
        l4[lane] = b4[lane];
        l4[lane + 64] = b4[lane + 64];
    }

    // ---- z b-frags (fp32 strided loads -> bf16 RNE)
    short8v zfr0[8], zfr1[8];
    {
        const float* zb0 = z_e + (size_t)b * CHW + hw0 + l15;
        const float* zb1 = zb0 + 16;
#pragma unroll
        for (int s = 0; s < 8; ++s) {
            float f0[8], f1[8];
#pragma unroll
            for (int j = 0; j < 8; ++j) {
                const size_t off = (size_t)(s * 32 + kg * 8 + j) * HW;
                f0[j] = zb0[off];
                f1[j] = zb1[off];
            }
            short8v v0, v1;
#pragma unroll
            for (int j = 0; j < 8; ++j) {
                v0[j] = (short)bf16_rne(f0[j]);
                v1[j] = (short)bf16_rne(f1[j]);
            }
            zfr0[s] = v0;
            zfr1[s] = v1;
        }
    }

    // ---- per-row filter state (rows l15 and 16+l15)
    float sc[2][4];
    int cd[2][4];
#pragma unroll
    for (int rt = 0; rt < 2; ++rt)
#pragma unroll
        for (int i = 0; i < 4; ++i) { sc[rt][i] = 3.0e38f; cd[rt][i] = 0x7fffffff; }

    // ---- FULL DRAIN: prologue DMAs + all z loads landed; slots 0..7 valid.
    asm volatile("s_waitcnt vmcnt(0)" ::: "memory");

#define TILE_EPILOGUE(T, A0, A1)                                               \
    {                                                                          \
        _Pragma("unroll") for (int r = 0; r < 4; ++r) {                        \
            const int code = (T) * 16 + 4 * kg + r;                            \
            const float Bk = lds_B[code];                                      \
            ins4(sc[0], cd[0], Bk - 2.0f * (A0)[r], code);                     \
            ins4(sc[1], cd[1], Bk - 2.0f * (A1)[r], code);                     \
        }                                                                      \
    }

    for (int t = 0; t < 31; ++t) {
        float4v a0 = {0.f, 0.f, 0.f, 0.f};
        float4v a1 = {0.f, 0.f, 0.f, 0.f};
#pragma unroll
        for (int s = 0; s < 8; ++s) {
            const int i = t * 8 + s;
            asm volatile("s_waitcnt vmcnt(7)" ::: "memory");
            const short8v a = *reinterpret_cast<const short8v*>(
                ring + (i & 15) * 1024 + lane * 16);
            a0 = __builtin_amdgcn_mfma_f32_16x16x32_bf16(a, zfr0[s], a0, 0, 0, 0);
            a1 = __builtin_amdgcn_mfma_f32_16x16x32_bf16(a, zfr1[s], a1, 0, 0, 0);
            GLOAD_LDS16(gA + (size_t)(i + 8) * 1024, ring + ((i + 8) & 15) * 1024);
        }
        TILE_EPILOGUE(t, a0, a1);
    }
    {
        asm volatile("s_waitcnt vmcnt(0)" ::: "memory");
        float4v a0 = {0.f, 0.f, 0.f, 0.f};
        float4v a1 = {0.f, 0.f, 0.f, 0.f};
#pragma unroll
        for (int s = 0; s < 8; ++s) {
            const int i = 248 + s;
            const short8v a = *reinterpret_cast<const short8v*>(
                ring + (i & 15) * 1024 + lane * 16);
            a0 = __builtin_amdgcn_mfma_f32_16x16x32_bf16(a, zfr0[s], a0, 0, 0, 0);
            a1 = __builtin_amdgcn_mfma_f32_16x16x32_bf16(a, zfr1[s], a1, 0, 0, 0);
        }
        TILE_EPILOGUE(31, a0, a1);
    }
#undef TILE_EPILOGUE

    // ---- per-row resolution -> pmeta[row] (no atomics, no compaction)
#pragma unroll
    for (int rt = 0; rt < 2; ++rt) {
        float g = sc[rt][0];
        g = fminf(g, __shfl_xor(g, 16));
        g = fminf(g, __shfl_xor(g, 32));
        const float thr = g + EPS_CAND;
        int cnt = (sc[rt][0] <= thr) + (sc[rt][1] <= thr) +
                  (sc[rt][2] <= thr) + (sc[rt][3] <= thr);
        int total = cnt;
        total += __shfl_xor(total, 16);
        total += __shfl_xor(total, 32);
        int ovf = (cnt == 4) ? 1 : 0;
        ovf |= __shfl_xor(ovf, 16);
        ovf |= __shfl_xor(ovf, 32);
        int wc = (cnt >= 1) ? cd[rt][0] : 0x7fffffff;
        wc = min(wc, __shfl_xor(wc, 16));
        wc = min(wc, __shfl_xor(wc, 32));
        const int row = row0 + rt * 16 + l15;
        const bool pend = (total != 1) || ovf;

        // gather per-lane in-window code words to lanes < 16
        unsigned w0 = ((cnt >= 1) ? (unsigned)cd[rt][0] : 0xFFFFu) |
                      (((cnt >= 2) ? (unsigned)cd[rt][1] : 0xFFFFu) << 16);
        unsigned w1 = ((cnt >= 3) ? (unsigned)cd[rt][2] : 0xFFFFu) |
                      (((cnt >= 4) ? (unsigned)cd[rt][3] : 0xFFFFu) << 16);
        unsigned gw0[4], gw1[4];
#pragma unroll
        for (int q = 0; q < 4; ++q) {
            gw0[q] = __shfl(w0, q * 16 + l15);
            gw1[q] = __shfl(w1, q * 16 + l15);
        }
        if (lane < 16) {
            if (!pend) {
                pmeta[row] = RESOLVED | (u64)(unsigned)wc;
            } else {
                unsigned c0 = 1023u, c1 = 1023u, c2 = 1023u;
                int n = 0;
#pragma unroll
                for (int q = 0; q < 4; ++q)
#pragma unroll
                    for (int h = 0; h < 4; ++h) {
                        const unsigned v =
                            (h < 2) ? ((gw0[q] >> (h * 16)) & 0xFFFFu)
                                    : ((gw1[q] >> ((h - 2) * 16)) & 0xFFFFu);
                        const bool val = (v != 0xFFFFu);
                        c2 = (val && n == 2) ? v : c2;
                        c1 = (val && n == 1) ? v : c1;
                        c0 = (val && n == 0) ? v : c0;
                        n += val ? 1 : 0;
                    }
                const bool full = ovf || (n > 3);
                pmeta[row] = ((u64)(full ? 1 : 0) << 16) | ((u64)c0 << 17) |
                             ((u64)c1 << 27) | ((u64)c2 << 37);
            }
        }
    }
}

// ---------------------------------------------------------------------------
// Kernel 3: gather + exact resolution + ST write + loss partials.
// Block = (image b, 64 rows, all 256 channels); z tile LDS-resident (64KB,
// coalesced DMA). Pending rows resolved by 16-thread groups with the
// bitwise numpy fp32 chain (z from LDS, e from L2-hot cb).
__global__ __launch_bounds__(256, 2) void vq_gather3(
    const float* __restrict__ z_e, const float* __restrict__ cb,
    const float* __restrict__ Bv, const u64* __restrict__ pmeta,
    float* __restrict__ part, float* __restrict__ out) {
    __shared__ __align__(16) float zt[256][64];  // 64 KB, z[c][row]
    __shared__ int kidx[64];
    __shared__ int prow[64];
    __shared__ u64 pm[64];
    __shared__ int pcount;
    __shared__ float wpart[4];

    const int t = threadIdx.x;
    const int wv = t >> 6;
    const int lane = t & 63;
    const int blk = blockIdx.x;
    const int b = blk >> 4;
    const int hw0 = (blk & 15) * 64;
    const int row0 = blk * 64;
    const char* zg = (const char*)(z_e + (size_t)b * CHW + hw0);

    // ---- stage z tile: wave wv covers channels [wv*64, wv*64+64).
    // Instr i stages 4 channels x 64 floats = 1KB; lane l: channel
    // c0+(l>>4), bytes (l&15)*16. LDS dest linear -> zt[c][j] layout.
    {
        char* zl = (char*)&zt[0][0];
#pragma unroll
        for (int i = 0; i < 16; ++i) {
            const int c0 = wv * 64 + i * 4;
            GLOAD_LDS16(zg + (size_t)(c0 + (lane >> 4)) * 4096 + (lane & 15) * 16,
                        zl + (size_t)c0 * 256);
        }
    }
    if (t == 0) pcount = 0;
    asm volatile("s_waitcnt vmcnt(0)" ::: "memory");
    __syncthreads();  // zt complete, pcount = 0

    // ---- decode pmeta
    if (t < 64) {
        const u64 m = pmeta[row0 + t];
        if (m & RESOLVED) {
            kidx[t] = (int)(m & 1023u);
        } else {
            const int s = atomicAdd(&pcount, 1);
            prow[s] = t;
            pm[s] = m;
        }
    }
    __syncthreads();

    // ---- resolve pending rows: 16 groups of 16 threads.
    {
        const int g = t >> 4;
        const int j = t & 15;
        const int wbase = (t & 63) - j;  // group base lane within the wave
        const int np = pcount;
        for (int p = g; p < np; p += 16) {
            const int row = prow[p];
            const u64 m = pm[p];
            const bool full = ((m >> 16) & 1ull) != 0;
            const unsigned cc[3] = {(unsigned)((m >> 17) & 1023u),
                                    (unsigned)((m >> 27) & 1023u),
                                    (unsigned)((m >> 37) & 1023u)};
            // A = ||z||^2, exact numpy pairwise: 16 chains (this group's 16
            // threads), tree computed redundantly on all lanes via shfl.
            float ch;
            {
#pragma clang fp contract(off)
                const int half = j >> 3;
                const int j0 = j & 7;
                float v = zt[half * 128 + j0][row];
                ch = v * v;
                for (int i = 1; i < 16; ++i) {
                    float u = zt[half * 128 + 8 * i + j0][row];
                    ch += u * u;
                }
            }
            float aval;
            {
#pragma clang fp contract(off)
                float r0 = __shfl(ch, wbase + 0), r1 = __shfl(ch, wbase + 1),
                      r2 = __shfl(ch, wbase + 2), r3 = __shfl(ch, wbase + 3),
                      r4 = __shfl(ch, wbase + 4), r5 = __shfl(ch, wbase + 5),
                      r6 = __shfl(ch, wbase + 6), r7 = __shfl(ch, wbase + 7),
                      r8 = __shfl(ch, wbase + 8), r9 = __shfl(ch, wbase + 9),
                      ra = __shfl(ch, wbase + 10), rb = __shfl(ch, wbase + 11),
                      rc = __shfl(ch, wbase + 12), rd = __shfl(ch, wbase + 13),
                      re = __shfl(ch, wbase + 14), rf = __shfl(ch, wbase + 15);
                float lo = ((r0 + r1) + (r2 + r3)) + ((r4 + r5) + (r6 + r7));
                float hi = ((r8 + r9) + (ra + rb)) + ((rc + rd) + (re + rf));
                aval = lo + hi;
            }

            float bd = 3.0e38f;
            int bk = 0x7fffffff;
            if (!full) {
                if (j < 3 && cc[j] < 512u) {
                    const int k = (int)cc[j];
                    const float* ep = cb + (size_t)k * D;
                    float a = 0.f;
#pragma unroll 8
                    for (int c = 0; c < D; ++c) a = fmaf(zt[c][row], ep[c], a);
                    {
#pragma clang fp contract(off)
                        float t1 = aval + Bv[k];
                        bd = t1 - 2.0f * a;
                    }
                    bk = k;
                }
            } else {
                for (int m2 = 0; m2 < 32; ++m2) {
                    const int k = j + 16 * m2;
                    const float* ep = cb + (size_t)k * D;
                    float a = 0.f;
#pragma unroll 8
                    for (int c = 0; c < D; ++c) a = fmaf(zt[c][row], ep[c], a);
                    float dv;
                    {
#pragma clang fp contract(off)
                        float t1 = aval + Bv[k];
                        dv = t1 - 2.0f * a;
                    }
                    if (dv < bd || (dv == bd && k < bk)) { bd = dv; bk = k; }
                }
            }
#pragma unroll
            for (int s = 1; s < 16; s <<= 1) {
                float od = __shfl_xor(bd, s);
                int ok = __shfl_xor(bk, s);
                if (od < bd || (od == bd && ok < bk)) { bd = od; bk = ok; }
            }
            if (j == 0) kidx[row] = bk;
        }
    }
    __syncthreads();

    // ---- gather / ST write / index output / loss partial (z from LDS)
    if (t < 64) out[IDX_OFF + row0 + t] = (float)kidx[t];
    {
        const int j = t & 63;       // row
        const int cq = t >> 6;      // channel quarter (64 channels)
        const int kme = kidx[j];
        const float* ep = cb + (size_t)kme * D;
        float* ob = out + (size_t)b * CHW + hw0 + j;
        float accum = 0.f;
#pragma unroll 4
        for (int i = 0; i < 64; ++i) {
            const int c = cq * 64 + i;
            const float z = zt[c][j];
            const float e = ep[c];
            ob[(size_t)c * HW] = z + (e - z);
            const float df = z - e;
            accum = fmaf(df, df, accum);
        }
#pragma unroll
        for (int s = 1; s < 64; s <<= 1) accum += __shfl_xor(accum, s);
        if (lane == 0) wpart[wv] = accum;
    }
    __syncthreads();
    if (t == 0) part[blk] = (wpart[0] + wpart[1]) + (wpart[2] + wpart[3]);
}

// ---------------------------------------------------------------------------
// Kernel 4: final loss reduction (1024 partials, fp64, deterministic).
__global__ void vq_finish(const float* __restrict__ part, float* __restrict__ out) {
    const int t = threadIdx.x;
    double s = 0.0;
#pragma unroll
    for (int i = 0; i < 4; ++i) s += (double)part[t + 256 * i];
#pragma unroll
    for (int m = 1; m < 64; m <<= 1) s += __shfl_xor(s, m);
    __shared__ double wsum[4];
    if ((t & 63) == 0) wsum[t >> 6] = s;
    __syncthreads();
    if (t == 0) {
        double mean = (wsum[0] + wsum[1] + wsum[2] + wsum[3]) / (double)ZQ_SIZE;
        out[LOSS0_OFF] = (float)mean;
        out[LOSS1_OFF] = (float)mean;
    }
}

// ---------------------------------------------------------------------------
extern "C" void kernel_launch(void* const* d_in, const int* in_sizes, int n_in,
                              void* d_out, int out_size, void* d_ws, size_t ws_size,
                              hipStream_t stream) {
    const float* z_e = (const float*)d_in[0];
    const float* cb = (const float*)d_in[1];
    float* out = (float*)d_out;
    float* ws = (float*)d_ws;

    const ushort_t* ehb = (const ushort_t*)ws;
    float* Bv = ws + WS_B;
    float* part = ws + WS_PART;
    u64* pmeta = (u64*)(ws + WS_PMETA);

    vq_prep<<<K, D, 0, stream>>>(cb, ws);
    vq_argmin7<<<NBLK_A, 64, 0, stream>>>(z_e, ehb, Bv, pmeta);
    vq_gather3<<<NBLK_G, 256, 0, stream>>>(z_e, cb, Bv, pmeta, part, out);
    vq_finish<<<1, 256, 0, stream>>>(part, out);
}

// Round 20
// 143.383 us; speedup vs baseline: 1.8591x; 1.5294x over previous
//
#include <hip/hip_runtime.h>

// VQ-VAE VectorQuantizer forward for MI355X (gfx950).
// Pipeline: prep -> argmin7 (barrier-free MFMA filter, 16-slot DMA ring,
// writes per-row pmeta) -> gather3 (z tile in LDS; resolves pending rows
// with the bitwise-exact numpy fp32 chain; gather/ST/loss; index output)
// -> finish.
// z_e: (64, 256, 32, 32) fp32; codebook: (512, 256) fp32.
// Outputs concatenated in d_out (float32):
//   [0, 16777216)        z_q_st ; [16777216] commit loss ; [+1] codebook loss
//   [16777218, +65536)   indices (as float)
//
// Index semantics: bitwise emulation of numpy-fp32
//   d = ||z||^2 + ||e||^2 - 2*matmul(z, e.T); idx = argmin (first occurrence).
//
// ROUND-19 POST-MORTEM: round-17's straggler fix never ran — compile error:
// '#pragma clang fp' placed mid-compound-statement in the full-row aval
// tree. Fixed by wrapping that tree in its own block. Logic unchanged:
// full pending rows resolved block-cooperatively (256 threads x 2
// interleaved chains, tie-correct reduce); candidate rows (n<=3) keep
// 16-thread-group chains. All exact numerics byte-identical.

typedef __attribute__((ext_vector_type(8))) short short8v;
typedef __attribute__((ext_vector_type(4))) float float4v;
typedef unsigned short ushort_t;
typedef unsigned long long u64;

#define GLOAD_LDS16(gsrc, ldst)                                                \
    __builtin_amdgcn_global_load_lds(                                          \
        (const __attribute__((address_space(1))) unsigned*)(gsrc),             \
        (__attribute__((address_space(3))) unsigned*)(ldst), 16, 0, 0)

namespace {
constexpr int K = 512;
constexpr int D = 256;
constexpr int HW = 1024;
constexpr int NROWS = 65536;
constexpr int CHW = D * HW;

constexpr int ZQ_SIZE = 64 * CHW;
constexpr int LOSS0_OFF = ZQ_SIZE;
constexpr int LOSS1_OFF = ZQ_SIZE + 1;
constexpr int IDX_OFF = ZQ_SIZE + 2;

// workspace layout (float offsets)
// ehb: frag-blocked bf16 codebook: step n = t*8+s (tile t: 16 codes, s: 32 d),
// lane = kg*16+l15: ehb[(n*64 + lane)*8 + j] = bf16(cb[t*16+l15][s*32+kg*8+j])
constexpr int WS_EH_FLOATS = (K * D) / 2;
constexpr int WS_B = WS_EH_FLOATS;          // ||e_k||^2 exact, 512
constexpr int WS_PART = WS_B + K;           // loss partials, 1024
constexpr int WS_PMETA = WS_PART + 1024;    // u64 per row, 2*65536 floats

constexpr int NBLK_A = NROWS / 32;          // 2048 blocks x 1 wave x 32 rows
constexpr int NBLK_G = NROWS / 64;          // 1024 gather blocks (64 rows)

constexpr float EPS_CAND = 1.5e-3f;
constexpr u64 RESOLVED = 1ull << 63;
}  // namespace

__device__ __forceinline__ ushort_t bf16_rne(float f) {
    unsigned u = __float_as_uint(f);
    u += 0x7fffu + ((u >> 16) & 1u);
    return (ushort_t)(u >> 16);
}

__device__ __forceinline__ void ins4(float* sc, int* cd, float s, int k) {
    if (s < sc[3]) { sc[3] = s; cd[3] = k; }
    if (sc[3] < sc[2]) { float tf = sc[2]; sc[2] = sc[3]; sc[3] = tf;
                         int ti = cd[2]; cd[2] = cd[3]; cd[3] = ti; }
    if (sc[2] < sc[1]) { float tf = sc[1]; sc[1] = sc[2]; sc[2] = tf;
                         int ti = cd[1]; cd[1] = cd[2]; cd[2] = ti; }
    if (sc[1] < sc[0]) { float tf = sc[0]; sc[0] = sc[1]; sc[1] = tf;
                         int ti = cd[0]; cd[0] = cd[1]; cd[1] = ti; }
}

// ---------------------------------------------------------------------------
// Kernel 1: frag-blocked bf16 codebook + exact numpy-pairwise ||e_k||^2.
__global__ void vq_prep(const float* __restrict__ cb, float* __restrict__ ws) {
    const int k = blockIdx.x;
    const int t = threadIdx.x;  // == d
    ushort_t* ehb = (ushort_t*)ws;
    {
        const int tt = k >> 4, l15 = k & 15;
        const int s = t >> 5, kg = (t >> 3) & 3, j = t & 7;
        ehb[(size_t)(((tt * 8 + s) * 64) + kg * 16 + l15) * 8 + j] =
            bf16_rne(cb[k * D + t]);
    }
    __shared__ float r16[16];
    if (t < 16) {
#pragma clang fp contract(off)
        const float* x = cb + k * D + (t >> 3) * 128;
        const int j = t & 7;
        float v = x[j];
        float r = v * v;
        for (int i = 1; i < 16; ++i) {
            float w = x[8 * i + j];
            r += w * w;
        }
        r16[t] = r;
    }
    __syncthreads();
    if (t == 0) {
#pragma clang fp contract(off)
        float lo = ((r16[0] + r16[1]) + (r16[2] + r16[3])) +
                   ((r16[4] + r16[5]) + (r16[6] + r16[7]));
        float hi = ((r16[8] + r16[9]) + (r16[10] + r16[11])) +
                   ((r16[12] + r16[13]) + (r16[14] + r16[15]));
        ws[WS_B + k] = lo + hi;
    }
}

// ---------------------------------------------------------------------------
// Kernel 2: argmin filter. ONE wave per block (64 threads), 32 rows, zero
// barriers. a-frags stream via a 16-slot wave-private global_load_lds ring:
// read slot i&15, refill slot (i+8)&15; s_waitcnt vmcnt(7) certifies the
// slot being read. Tail writes ONE pmeta word per row.
__global__ __launch_bounds__(64, 3) void vq_argmin7(
    const float* __restrict__ z_e, const ushort_t* __restrict__ ehb,
    const float* __restrict__ Bv, u64* __restrict__ pmeta) {
    __shared__ __align__(16) char ring[16 * 1024];  // 16 slots x 1KB
    __shared__ float lds_B[K];                      // 2 KB

    const int lane = threadIdx.x;
    const int wid = blockIdx.x;
    const int row0 = wid * 32;
    const int b = row0 >> 10;
    const int hw0 = row0 & 1023;
    const int l15 = lane & 15;
    const int kg = lane >> 4;

    // ---- prologue DMA: steps 0..7 into slots 0..7.
    const char* gA = (const char*)ehb + (size_t)lane * 16;
#pragma unroll
    for (int n = 0; n < 8; ++n)
        GLOAD_LDS16(gA + (size_t)n * 1024, ring + n * 1024);

    // ---- stage Bv -> LDS (own wave)
    {
        const float4* b4 = reinterpret_cast<const float4*>(Bv);
        float4* l4 = reinterpret_cast<float4*>(lds_B);
        l4[lane] = b4[lane];
        l4[lane + 64] = b4[lane + 64];
    }

    // ---- z b-frags (fp32 strided loads -> bf16 RNE)
    short8v zfr0[8], zfr1[8];
    {
        const float* zb0 = z_e + (size_t)b * CHW + hw0 + l15;
        const float* zb1 = zb0 + 16;
#pragma unroll
        for (int s = 0; s < 8; ++s) {
            float f0[8], f1[8];
#pragma unroll
            for (int j = 0; j < 8; ++j) {
                const size_t off = (size_t)(s * 32 + kg * 8 + j) * HW;
                f0[j] = zb0[off];
                f1[j] = zb1[off];
            }
            short8v v0, v1;
#pragma unroll
            for (int j = 0; j < 8; ++j) {
                v0[j] = (short)bf16_rne(f0[j]);
                v1[j] = (short)bf16_rne(f1[j]);
            }
            zfr0[s] = v0;
            zfr1[s] = v1;
        }
    }

    // ---- per-row filter state (rows l15 and 16+l15)
    float sc[2][4];
    int cd[2][4];
#pragma unroll
    for (int rt = 0; rt < 2; ++rt)
#pragma unroll
        for (int i = 0; i < 4; ++i) { sc[rt][i] = 3.0e38f; cd[rt][i] = 0x7fffffff; }

    // ---- FULL DRAIN: prologue DMAs + all z loads landed; slots 0..7 valid.
    asm volatile("s_waitcnt vmcnt(0)" ::: "memory");

#define TILE_EPILOGUE(T, A0, A1)                                               \
    {                                                                          \
        _Pragma("unroll") for (int r = 0; r < 4; ++r) {                        \
            const int code = (T) * 16 + 4 * kg + r;                            \
            const float Bk = lds_B[code];                                      \
            ins4(sc[0], cd[0], Bk - 2.0f * (A0)[r], code);                     \
            ins4(sc[1], cd[1], Bk - 2.0f * (A1)[r], code);                     \
        }                                                                      \
    }

    for (int t = 0; t < 31; ++t) {
        float4v a0 = {0.f, 0.f, 0.f, 0.f};
        float4v a1 = {0.f, 0.f, 0.f, 0.f};
#pragma unroll
        for (int s = 0; s < 8; ++s) {
            const int i = t * 8 + s;
            asm volatile("s_waitcnt vmcnt(7)" ::: "memory");
            const short8v a = *reinterpret_cast<const short8v*>(
                ring + (i & 15) * 1024 + lane * 16);
            a0 = __builtin_amdgcn_mfma_f32_16x16x32_bf16(a, zfr0[s], a0, 0, 0, 0);
            a1 = __builtin_amdgcn_mfma_f32_16x16x32_bf16(a, zfr1[s], a1, 0, 0, 0);
            GLOAD_LDS16(gA + (size_t)(i + 8) * 1024, ring + ((i + 8) & 15) * 1024);
        }
        TILE_EPILOGUE(t, a0, a1);
    }
    {
        asm volatile("s_waitcnt vmcnt(0)" ::: "memory");
        float4v a0 = {0.f, 0.f, 0.f, 0.f};
        float4v a1 = {0.f, 0.f, 0.f, 0.f};
#pragma unroll
        for (int s = 0; s < 8; ++s) {
            const int i = 248 + s;
            const short8v a = *reinterpret_cast<const short8v*>(
                ring + (i & 15) * 1024 + lane * 16);
            a0 = __builtin_amdgcn_mfma_f32_16x16x32_bf16(a, zfr0[s], a0, 0, 0, 0);
            a1 = __builtin_amdgcn_mfma_f32_16x16x32_bf16(a, zfr1[s], a1, 0, 0, 0);
        }
        TILE_EPILOGUE(31, a0, a1);
    }
#undef TILE_EPILOGUE

    // ---- per-row resolution -> pmeta[row] (no atomics, no compaction)
#pragma unroll
    for (int rt = 0; rt < 2; ++rt) {
        float g = sc[rt][0];
        g = fminf(g, __shfl_xor(g, 16));
        g = fminf(g, __shfl_xor(g, 32));
        const float thr = g + EPS_CAND;
        int cnt = (sc[rt][0] <= thr) + (sc[rt][1] <= thr) +
                  (sc[rt][2] <= thr) + (sc[rt][3] <= thr);
        int total = cnt;
        total += __shfl_xor(total, 16);
        total += __shfl_xor(total, 32);
        int ovf = (cnt == 4) ? 1 : 0;
        ovf |= __shfl_xor(ovf, 16);
        ovf |= __shfl_xor(ovf, 32);
        int wc = (cnt >= 1) ? cd[rt][0] : 0x7fffffff;
        wc = min(wc, __shfl_xor(wc, 16));
        wc = min(wc, __shfl_xor(wc, 32));
        const int row = row0 + rt * 16 + l15;
        const bool pend = (total != 1) || ovf;

        unsigned w0 = ((cnt >= 1) ? (unsigned)cd[rt][0] : 0xFFFFu) |
                      (((cnt >= 2) ? (unsigned)cd[rt][1] : 0xFFFFu) << 16);
        unsigned w1 = ((cnt >= 3) ? (unsigned)cd[rt][2] : 0xFFFFu) |
                      (((cnt >= 4) ? (unsigned)cd[rt][3] : 0xFFFFu) << 16);
        unsigned gw0[4], gw1[4];
#pragma unroll
        for (int q = 0; q < 4; ++q) {
            gw0[q] = __shfl(w0, q * 16 + l15);
            gw1[q] = __shfl(w1, q * 16 + l15);
        }
        if (lane < 16) {
            if (!pend) {
                pmeta[row] = RESOLVED | (u64)(unsigned)wc;
            } else {
                unsigned c0 = 1023u, c1 = 1023u, c2 = 1023u;
                int n = 0;
#pragma unroll
                for (int q = 0; q < 4; ++q)
#pragma unroll
                    for (int h = 0; h < 4; ++h) {
                        const unsigned v =
                            (h < 2) ? ((gw0[q] >> (h * 16)) & 0xFFFFu)
                                    : ((gw1[q] >> ((h - 2) * 16)) & 0xFFFFu);
                        const bool val = (v != 0xFFFFu);
                        c2 = (val && n == 2) ? v : c2;
                        c1 = (val && n == 1) ? v : c1;
                        c0 = (val && n == 0) ? v : c0;
                        n += val ? 1 : 0;
                    }
                const bool full = ovf || (n > 3);
                pmeta[row] = ((u64)(full ? 1 : 0) << 16) | ((u64)c0 << 17) |
                             ((u64)c1 << 27) | ((u64)c2 << 37);
            }
        }
    }
}

// ---------------------------------------------------------------------------
// Kernel 3: gather + exact resolution + ST write + loss partials.
// Block = (image b, 64 rows, all 256 channels); z tile LDS-resident (64KB,
// coalesced DMA). Candidate rows (n<=3): 16-thread-group chains.
// Full rows: block-cooperative (256 threads x 2 interleaved chains).
__global__ __launch_bounds__(256, 2) void vq_gather3(
    const float* __restrict__ z_e, const float* __restrict__ cb,
    const float* __restrict__ Bv, const u64* __restrict__ pmeta,
    float* __restrict__ part, float* __restrict__ out) {
    __shared__ __align__(16) float zt[256][64];  // 64 KB, z[c][row]
    __shared__ int kidx[64];
    __shared__ int prow[64];
    __shared__ u64 pm[64];
    __shared__ int frow[64];
    __shared__ int pcount, fcount;
    __shared__ float faval;
    __shared__ float fbd[4];
    __shared__ int fbk[4];
    __shared__ float wpart[4];

    const int t = threadIdx.x;
    const int wv = t >> 6;
    const int lane = t & 63;
    const int blk = blockIdx.x;
    const int b = blk >> 4;
    const int hw0 = (blk & 15) * 64;
    const int row0 = blk * 64;
    const char* zg = (const char*)(z_e + (size_t)b * CHW + hw0);

    // ---- stage z tile: wave wv covers channels [wv*64, wv*64+64).
    {
        char* zl = (char*)&zt[0][0];
#pragma unroll
        for (int i = 0; i < 16; ++i) {
            const int c0 = wv * 64 + i * 4;
            GLOAD_LDS16(zg + (size_t)(c0 + (lane >> 4)) * 4096 + (lane & 15) * 16,
                        zl + (size_t)c0 * 256);
        }
    }
    if (t == 0) { pcount = 0; fcount = 0; }
    asm volatile("s_waitcnt vmcnt(0)" ::: "memory");
    __syncthreads();  // zt complete, counters zeroed

    // ---- decode pmeta
    if (t < 64) {
        const u64 m = pmeta[row0 + t];
        if (m & RESOLVED) {
            kidx[t] = (int)(m & 1023u);
        } else if ((m >> 16) & 1ull) {
            const int s = atomicAdd(&fcount, 1);
            frow[s] = t;
        } else {
            const int s = atomicAdd(&pcount, 1);
            prow[s] = t;
            pm[s] = m;
        }
    }
    __syncthreads();

    // ---- candidate rows (n<=3): 16 groups of 16 threads.
    {
        const int g = t >> 4;
        const int j = t & 15;
        const int wbase = (t & 63) - j;
        const int np = pcount;
        for (int p = g; p < np; p += 16) {
            const int row = prow[p];
            const u64 m = pm[p];
            const unsigned cc[3] = {(unsigned)((m >> 17) & 1023u),
                                    (unsigned)((m >> 27) & 1023u),
                                    (unsigned)((m >> 37) & 1023u)};
            float ch;
            {
#pragma clang fp contract(off)
                const int half = j >> 3;
                const int j0 = j & 7;
                float v = zt[half * 128 + j0][row];
                ch = v * v;
                for (int i = 1; i < 16; ++i) {
                    float u = zt[half * 128 + 8 * i + j0][row];
                    ch += u * u;
                }
            }
            float aval;
            {
#pragma clang fp contract(off)
                float r0 = __shfl(ch, wbase + 0), r1 = __shfl(ch, wbase + 1),
                      r2 = __shfl(ch, wbase + 2), r3 = __shfl(ch, wbase + 3),
                      r4 = __shfl(ch, wbase + 4), r5 = __shfl(ch, wbase + 5),
                      r6 = __shfl(ch, wbase + 6), r7 = __shfl(ch, wbase + 7),
                      r8 = __shfl(ch, wbase + 8), r9 = __shfl(ch, wbase + 9),
                      ra = __shfl(ch, wbase + 10), rb = __shfl(ch, wbase + 11),
                      rc = __shfl(ch, wbase + 12), rd = __shfl(ch, wbase + 13),
                      re = __shfl(ch, wbase + 14), rf = __shfl(ch, wbase + 15);
                float lo = ((r0 + r1) + (r2 + r3)) + ((r4 + r5) + (r6 + r7));
                float hi = ((r8 + r9) + (ra + rb)) + ((rc + rd) + (re + rf));
                aval = lo + hi;
            }

            float bd = 3.0e38f;
            int bk = 0x7fffffff;
            if (j < 3 && cc[j] < 512u) {
                const int k = (int)cc[j];
                const float* ep = cb + (size_t)k * D;
                float a = 0.f;
#pragma unroll 8
                for (int c = 0; c < D; ++c) a = fmaf(zt[c][row], ep[c], a);
                {
#pragma clang fp contract(off)
                    float t1 = aval + Bv[k];
                    bd = t1 - 2.0f * a;
                }
                bk = k;
            }
#pragma unroll
            for (int s = 1; s < 16; s <<= 1) {
                float od = __shfl_xor(bd, s);
                int ok = __shfl_xor(bk, s);
                if (od < bd || (od == bd && ok < bk)) { bd = od; bk = ok; }
            }
            if (j == 0) kidx[row] = bk;
        }
    }
    __syncthreads();

    // ---- full rows: block-cooperative, 2 interleaved chains per thread.
    {
        const int nf = fcount;
        for (int p = 0; p < nf; ++p) {
            const int row = frow[p];
            // aval: wave 0, redundant chains on j = lane&15
            if (wv == 0) {
                const int j = lane & 15;
                float ch;
                {
#pragma clang fp contract(off)
                    const int half = j >> 3;
                    const int j0 = j & 7;
                    float v = zt[half * 128 + j0][row];
                    ch = v * v;
                    for (int i = 1; i < 16; ++i) {
                        float u = zt[half * 128 + 8 * i + j0][row];
                        ch += u * u;
                    }
                }
                {
#pragma clang fp contract(off)
                    float r0 = __shfl(ch, 0), r1 = __shfl(ch, 1),
                          r2 = __shfl(ch, 2), r3 = __shfl(ch, 3),
                          r4 = __shfl(ch, 4), r5 = __shfl(ch, 5),
                          r6 = __shfl(ch, 6), r7 = __shfl(ch, 7),
                          r8 = __shfl(ch, 8), r9 = __shfl(ch, 9),
                          ra = __shfl(ch, 10), rb = __shfl(ch, 11),
                          rc = __shfl(ch, 12), rd = __shfl(ch, 13),
                          re = __shfl(ch, 14), rf = __shfl(ch, 15);
                    float lo = ((r0 + r1) + (r2 + r3)) + ((r4 + r5) + (r6 + r7));
                    float hi = ((r8 + r9) + (ra + rb)) + ((rc + rd) + (re + rf));
                    if (lane == 0) faval = lo + hi;
                }
            }
            __syncthreads();

            const float aval = faval;
            const int k0 = t;
            const int k1 = t + 256;
            const float* e0 = cb + (size_t)k0 * D;
            const float* e1 = cb + (size_t)k1 * D;
            float a0 = 0.f, a1 = 0.f;
#pragma unroll 8
            for (int c = 0; c < D; ++c) {
                const float z = zt[c][row];
                a0 = fmaf(z, e0[c], a0);
                a1 = fmaf(z, e1[c], a1);
            }
            float dv0, dv1;
            {
#pragma clang fp contract(off)
                float t0v = aval + Bv[k0];
                dv0 = t0v - 2.0f * a0;
                float t1v = aval + Bv[k1];
                dv1 = t1v - 2.0f * a1;
            }
            float bd = dv0;
            int bk = k0;
            if (dv1 < bd) { bd = dv1; bk = k1; }  // k0 < k1: tie keeps k0
#pragma unroll
            for (int s = 1; s < 64; s <<= 1) {
                float od = __shfl_xor(bd, s);
                int ok = __shfl_xor(bk, s);
                if (od < bd || (od == bd && ok < bk)) { bd = od; bk = ok; }
            }
            if (lane == 0) { fbd[wv] = bd; fbk[wv] = bk; }
            __syncthreads();
            if (t == 0) {
                float xbd = fbd[0];
                int xbk = fbk[0];
#pragma unroll
                for (int q = 1; q < 4; ++q) {
                    if (fbd[q] < xbd || (fbd[q] == xbd && fbk[q] < xbk)) {
                        xbd = fbd[q];
                        xbk = fbk[q];
                    }
                }
                kidx[row] = xbk;
            }
            __syncthreads();
        }
    }
    __syncthreads();

    // ---- gather / ST write / index output / loss partial (z from LDS)
    if (t < 64) out[IDX_OFF + row0 + t] = (float)kidx[t];
    {
        const int j = t & 63;       // row
        const int cq = t >> 6;      // channel quarter (64 channels)
        const int kme = kidx[j];
        const float* ep = cb + (size_t)kme * D;
        float* ob = out + (size_t)b * CHW + hw0 + j;
        float accum = 0.f;
#pragma unroll 4
        for (int i = 0; i < 64; ++i) {
            const int c = cq * 64 + i;
            const float z = zt[c][j];
            const float e = ep[c];
            ob[(size_t)c * HW] = z + (e - z);
            const float df = z - e;
            accum = fmaf(df, df, accum);
        }
#pragma unroll
        for (int s = 1; s < 64; s <<= 1) accum += __shfl_xor(accum, s);
        if (lane == 0) wpart[wv] = accum;
    }
    __syncthreads();
    if (t == 0) part[blk] = (wpart[0] + wpart[1]) + (wpart[2] + wpart[3]);
}

// ---------------------------------------------------------------------------
// Kernel 4: final loss reduction (1024 partials, fp64, deterministic).
__global__ void vq_finish(const float* __restrict__ part, float* __restrict__ out) {
    const int t = threadIdx.x;
    double s = 0.0;
#pragma unroll
    for (int i = 0; i < 4; ++i) s += (double)part[t + 256 * i];
#pragma unroll
    for (int m = 1; m < 64; m <<= 1) s += __shfl_xor(s, m);
    __shared__ double wsum[4];
    if ((t & 63) == 0) wsum[t >> 6] = s;
    __syncthreads();
    if (t == 0) {
        double mean = (wsum[0] + wsum[1] + wsum[2] + wsum[3]) / (double)ZQ_SIZE;
        out[LOSS0_OFF] = (float)mean;
        out[LOSS1_OFF] = (float)mean;
    }
}

// ---------------------------------------------------------------------------
extern "C" void kernel_launch(void* const* d_in, const int* in_sizes, int n_in,
                              void* d_out, int out_size, void* d_ws, size_t ws_size,
                              hipStream_t stream) {
    const float* z_e = (const float*)d_in[0];
    const float* cb = (const float*)d_in[1];
    float* out = (float*)d_out;
    float* ws = (float*)d_ws;

    const ushort_t* ehb = (const ushort_t*)ws;
    float* Bv = ws + WS_B;
    float* part = ws + WS_PART;
    u64* pmeta = (u64*)(ws + WS_PMETA);

    vq_prep<<<K, D, 0, stream>>>(cb, ws);
    vq_argmin7<<<NBLK_A, 64, 0, stream>>>(z_e, ehb, Bv, pmeta);
    vq_gather3<<<NBLK_G, 256, 0, stream>>>(z_e, cb, Bv, pmeta, part, out);
    vq_finish<<<1, 256, 0, stream>>>(part, out);
}

// Round 21
// 127.613 us; speedup vs baseline: 2.0889x; 1.1236x over previous
//
#include <hip/hip_runtime.h>

// VQ-VAE VectorQuantizer forward for MI355X (gfx950).
// Pipeline: prep -> argmin7 (barrier-free MFMA filter, 16-slot DMA ring,
// writes per-row pmeta) -> gather3 (32-row z tile in LDS; resolves pending
// rows with the bitwise-exact numpy fp32 chain; gather/ST/loss; index out)
// -> finish.
// z_e: (64, 256, 32, 32) fp32; codebook: (512, 256) fp32.
// Outputs concatenated in d_out (float32):
//   [0, 16777216)        z_q_st ; [16777216] commit loss ; [+1] codebook loss
//   [16777218, +65536)   indices (as float)
//
// Index semantics: bitwise emulation of numpy-fp32
//   d = ||z||^2 + ||e||^2 - 2*matmul(z, e.T); idx = argmin (first occurrence).
//
// ROUND-20 POST-MORTEM: gather3 (64-row tile, 67KB LDS, 2 blocks/CU, 1024
// blocks = 4/CU) ran its serial phase chain with only 2-deep block overlap:
// dur identical cold vs L3-warm, VALUBusy 6%, occupancy 10.8%. THIS ROUND:
// 32-row tiles (32KB LDS, launch_bounds(256,4) -> 4 blocks/CU, 2048 blocks),
// pmeta decode overlapped with the z-DMA drain, EPS 1.5e-3 -> 1.0e-3
// (bound: 2*max|s~-s| + numpy-quant slack ~ 5.4e-4; 1.85x margin) to cut
// the pending set ~33%. argmin7 and all exact numerics byte-identical.

typedef __attribute__((ext_vector_type(8))) short short8v;
typedef __attribute__((ext_vector_type(4))) float float4v;
typedef unsigned short ushort_t;
typedef unsigned long long u64;

#define GLOAD_LDS16(gsrc, ldst)                                                \
    __builtin_amdgcn_global_load_lds(                                          \
        (const __attribute__((address_space(1))) unsigned*)(gsrc),             \
        (__attribute__((address_space(3))) unsigned*)(ldst), 16, 0, 0)

namespace {
constexpr int K = 512;
constexpr int D = 256;
constexpr int HW = 1024;
constexpr int NROWS = 65536;
constexpr int CHW = D * HW;

constexpr int ZQ_SIZE = 64 * CHW;
constexpr int LOSS0_OFF = ZQ_SIZE;
constexpr int LOSS1_OFF = ZQ_SIZE + 1;
constexpr int IDX_OFF = ZQ_SIZE + 2;

// workspace layout (float offsets)
// ehb: frag-blocked bf16 codebook: step n = t*8+s (tile t: 16 codes, s: 32 d),
// lane = kg*16+l15: ehb[(n*64 + lane)*8 + j] = bf16(cb[t*16+l15][s*32+kg*8+j])
constexpr int WS_EH_FLOATS = (K * D) / 2;
constexpr int WS_B = WS_EH_FLOATS;          // ||e_k||^2 exact, 512
constexpr int WS_PART = WS_B + K;           // loss partials, 2048
constexpr int WS_PMETA = WS_PART + 2048;    // u64 per row, 2*65536 floats

constexpr int NBLK_A = NROWS / 32;          // 2048 argmin blocks (32 rows)
constexpr int NBLK_G = NROWS / 32;          // 2048 gather blocks (32 rows)

constexpr float EPS_CAND = 1.0e-3f;
constexpr u64 RESOLVED = 1ull << 63;
}  // namespace

__device__ __forceinline__ ushort_t bf16_rne(float f) {
    unsigned u = __float_as_uint(f);
    u += 0x7fffu + ((u >> 16) & 1u);
    return (ushort_t)(u >> 16);
}

__device__ __forceinline__ void ins4(float* sc, int* cd, float s, int k) {
    if (s < sc[3]) { sc[3] = s; cd[3] = k; }
    if (sc[3] < sc[2]) { float tf = sc[2]; sc[2] = sc[3]; sc[3] = tf;
                         int ti = cd[2]; cd[2] = cd[3]; cd[3] = ti; }
    if (sc[2] < sc[1]) { float tf = sc[1]; sc[1] = sc[2]; sc[2] = tf;
                         int ti = cd[1]; cd[1] = cd[2]; cd[2] = ti; }
    if (sc[1] < sc[0]) { float tf = sc[0]; sc[0] = sc[1]; sc[1] = tf;
                         int ti = cd[0]; cd[0] = cd[1]; cd[1] = ti; }
}

// ---------------------------------------------------------------------------
// Kernel 1: frag-blocked bf16 codebook + exact numpy-pairwise ||e_k||^2.
__global__ void vq_prep(const float* __restrict__ cb, float* __restrict__ ws) {
    const int k = blockIdx.x;
    const int t = threadIdx.x;  // == d
    ushort_t* ehb = (ushort_t*)ws;
    {
        const int tt = k >> 4, l15 = k & 15;
        const int s = t >> 5, kg = (t >> 3) & 3, j = t & 7;
        ehb[(size_t)(((tt * 8 + s) * 64) + kg * 16 + l15) * 8 + j] =
            bf16_rne(cb[k * D + t]);
    }
    __shared__ float r16[16];
    if (t < 16) {
#pragma clang fp contract(off)
        const float* x = cb + k * D + (t >> 3) * 128;
        const int j = t & 7;
        float v = x[j];
        float r = v * v;
        for (int i = 1; i < 16; ++i) {
            float w = x[8 * i + j];
            r += w * w;
        }
        r16[t] = r;
    }
    __syncthreads();
    if (t == 0) {
#pragma clang fp contract(off)
        float lo = ((r16[0] + r16[1]) + (r16[2] + r16[3])) +
                   ((r16[4] + r16[5]) + (r16[6] + r16[7]));
        float hi = ((r16[8] + r16[9]) + (r16[10] + r16[11])) +
                   ((r16[12] + r16[13]) + (r16[14] + r16[15]));
        ws[WS_B + k] = lo + hi;
    }
}

// ---------------------------------------------------------------------------
// Kernel 2: argmin filter. ONE wave per block (64 threads), 32 rows, zero
// barriers. a-frags stream via a 16-slot wave-private global_load_lds ring:
// read slot i&15, refill slot (i+8)&15; s_waitcnt vmcnt(7) certifies the
// slot being read. Tail writes ONE pmeta word per row.
__global__ __launch_bounds__(64, 3) void vq_argmin7(
    const float* __restrict__ z_e, const ushort_t* __restrict__ ehb,
    const float* __restrict__ Bv, u64* __restrict__ pmeta) {
    __shared__ __align__(16) char ring[16 * 1024];  // 16 slots x 1KB
    __shared__ float lds_B[K];                      // 2 KB

    const int lane = threadIdx.x;
    const int wid = blockIdx.x;
    const int row0 = wid * 32;
    const int b = row0 >> 10;
    const int hw0 = row0 & 1023;
    const int l15 = lane & 15;
    const int kg = lane >> 4;

    // ---- prologue DMA: steps 0..7 into slots 0..7.
    const char* gA = (const char*)ehb + (size_t)lane * 16;
#pragma unroll
    for (int n = 0; n < 8; ++n)
        GLOAD_LDS16(gA + (size_t)n * 1024, ring + n * 1024);

    // ---- stage Bv -> LDS (own wave)
    {
        const float4* b4 = reinterpret_cast<const float4*>(Bv);
        float4* l4 = reinterpret_cast<float4*>(lds_B);
        l4[lane] = b4[lane];
        l4[lane + 64] = b4[lane + 64];
    }

    // ---- z b-frags (fp32 strided loads -> bf16 RNE)
    short8v zfr0[8], zfr1[8];
    {
        const float* zb0 = z_e + (size_t)b * CHW + hw0 + l15;
        const float* zb1 = zb0 + 16;
#pragma unroll
        for (int s = 0; s < 8; ++s) {
            float f0[8], f1[8];
#pragma unroll
            for (int j = 0; j < 8; ++j) {
                const size_t off = (size_t)(s * 32 + kg * 8 + j) * HW;
                f0[j] = zb0[off];
                f1[j] = zb1[off];
            }
            short8v v0, v1;
#pragma unroll
            for (int j = 0; j < 8; ++j) {
                v0[j] = (short)bf16_rne(f0[j]);
                v1[j] = (short)bf16_rne(f1[j]);
            }
            zfr0[s] = v0;
            zfr1[s] = v1;
        }
    }

    // ---- per-row filter state (rows l15 and 16+l15)
    float sc[2][4];
    int cd[2][4];
#pragma unroll
    for (int rt = 0; rt < 2; ++rt)
#pragma unroll
        for (int i = 0; i < 4; ++i) { sc[rt][i] = 3.0e38f; cd[rt][i] = 0x7fffffff; }

    // ---- FULL DRAIN: prologue DMAs + all z loads landed; slots 0..7 valid.
    asm volatile("s_waitcnt vmcnt(0)" ::: "memory");

#define TILE_EPILOGUE(T, A0, A1)                                               \
    {                                                                          \
        _Pragma("unroll") for (int r = 0; r < 4; ++r) {                        \
            const int code = (T) * 16 + 4 * kg + r;                            \
            const float Bk = lds_B[code];                                      \
            ins4(sc[0], cd[0], Bk - 2.0f * (A0)[r], code);                     \
            ins4(sc[1], cd[1], Bk - 2.0f * (A1)[r], code);                     \
        }                                                                      \
    }

    for (int t = 0; t < 31; ++t) {
        float4v a0 = {0.f, 0.f, 0.f, 0.f};
        float4v a1 = {0.f, 0.f, 0.f, 0.f};
#pragma unroll
        for (int s = 0; s < 8; ++s) {
            const int i = t * 8 + s;
            asm volatile("s_waitcnt vmcnt(7)" ::: "memory");
            const short8v a = *reinterpret_cast<const short8v*>(
                ring + (i & 15) * 1024 + lane * 16);
            a0 = __builtin_amdgcn_mfma_f32_16x16x32_bf16(a, zfr0[s], a0, 0, 0, 0);
            a1 = __builtin_amdgcn_mfma_f32_16x16x32_bf16(a, zfr1[s], a1, 0, 0, 0);
            GLOAD_LDS16(gA + (size_t)(i + 8) * 1024, ring + ((i + 8) & 15) * 1024);
        }
        TILE_EPILOGUE(t, a0, a1);
    }
    {
        asm volatile("s_waitcnt vmcnt(0)" ::: "memory");
        float4v a0 = {0.f, 0.f, 0.f, 0.f};
        float4v a1 = {0.f, 0.f, 0.f, 0.f};
#pragma unroll
        for (int s = 0; s < 8; ++s) {
            const int i = 248 + s;
            const short8v a = *reinterpret_cast<const short8v*>(
                ring + (i & 15) * 1024 + lane * 16);
            a0 = __builtin_amdgcn_mfma_f32_16x16x32_bf16(a, zfr0[s], a0, 0, 0, 0);
            a1 = __builtin_amdgcn_mfma_f32_16x16x32_bf16(a, zfr1[s], a1, 0, 0, 0);
        }
        TILE_EPILOGUE(31, a0, a1);
    }
#undef TILE_EPILOGUE

    // ---- per-row resolution -> pmeta[row] (no atomics, no compaction)
#pragma unroll
    for (int rt = 0; rt < 2; ++rt) {
        float g = sc[rt][0];
        g = fminf(g, __shfl_xor(g, 16));
        g = fminf(g, __shfl_xor(g, 32));
        const float thr = g + EPS_CAND;
        int cnt = (sc[rt][0] <= thr) + (sc[rt][1] <= thr) +
                  (sc[rt][2] <= thr) + (sc[rt][3] <= thr);
        int total = cnt;
        total += __shfl_xor(total, 16);
        total += __shfl_xor(total, 32);
        int ovf = (cnt == 4) ? 1 : 0;
        ovf |= __shfl_xor(ovf, 16);
        ovf |= __shfl_xor(ovf, 32);
        int wc = (cnt >= 1) ? cd[rt][0] : 0x7fffffff;
        wc = min(wc, __shfl_xor(wc, 16));
        wc = min(wc, __shfl_xor(wc, 32));
        const int row = row0 + rt * 16 + l15;
        const bool pend = (total != 1) || ovf;

        unsigned w0 = ((cnt >= 1) ? (unsigned)cd[rt][0] : 0xFFFFu) |
                      (((cnt >= 2) ? (unsigned)cd[rt][1] : 0xFFFFu) << 16);
        unsigned w1 = ((cnt >= 3) ? (unsigned)cd[rt][2] : 0xFFFFu) |
                      (((cnt >= 4) ? (unsigned)cd[rt][3] : 0xFFFFu) << 16);
        unsigned gw0[4], gw1[4];
#pragma unroll
        for (int q = 0; q < 4; ++q) {
            gw0[q] = __shfl(w0, q * 16 + l15);
            gw1[q] = __shfl(w1, q * 16 + l15);
        }
        if (lane < 16) {
            if (!pend) {
                pmeta[row] = RESOLVED | (u64)(unsigned)wc;
            } else {
                unsigned c0 = 1023u, c1 = 1023u, c2 = 1023u;
                int n = 0;
#pragma unroll
                for (int q = 0; q < 4; ++q)
#pragma unroll
                    for (int h = 0; h < 4; ++h) {
                        const unsigned v =
                            (h < 2) ? ((gw0[q] >> (h * 16)) & 0xFFFFu)
                                    : ((gw1[q] >> ((h - 2) * 16)) & 0xFFFFu);
                        const bool val = (v != 0xFFFFu);
                        c2 = (val && n == 2) ? v : c2;
                        c1 = (val && n == 1) ? v : c1;
                        c0 = (val && n == 0) ? v : c0;
                        n += val ? 1 : 0;
                    }
                const bool full = ovf || (n > 3);
                pmeta[row] = ((u64)(full ? 1 : 0) << 16) | ((u64)c0 << 17) |
                             ((u64)c1 << 27) | ((u64)c2 << 37);
            }
        }
    }
}

// ---------------------------------------------------------------------------
// Kernel 3: gather + exact resolution + ST write + loss partials.
// Block = 32 rows x all 256 channels; z tile LDS-resident (32KB, coalesced
// DMA, 4 blocks/CU). Candidate rows (n<=3): 16-thread-group chains.
// Full rows: block-cooperative (256 threads x 2 interleaved chains).
__global__ __launch_bounds__(256, 4) void vq_gather3(
    const float* __restrict__ z_e, const float* __restrict__ cb,
    const float* __restrict__ Bv, const u64* __restrict__ pmeta,
    float* __restrict__ part, float* __restrict__ out) {
    __shared__ __align__(16) float zt[256][32];  // 32 KB, z[c][row]
    __shared__ int kidx[32];
    __shared__ int prow[32];
    __shared__ u64 pm[32];
    __shared__ int frow[32];
    __shared__ int pcount, fcount;
    __shared__ float faval;
    __shared__ float fbd[4];
    __shared__ int fbk[4];
    __shared__ float wpart[4];

    const int t = threadIdx.x;
    const int wv = t >> 6;
    const int lane = t & 63;
    const int blk = blockIdx.x;
    const int b = blk >> 5;
    const int hw0 = (blk & 31) * 32;
    const int row0 = blk * 32;
    const char* zg = (const char*)(z_e + (size_t)b * CHW + hw0);

    // ---- stage z tile: wave wv covers channels [wv*64, wv*64+64).
    // Instr i stages 8 channels x 32 floats = 1KB; lane l: channel
    // c0+(l>>3), bytes (l&7)*16. LDS dest linear -> zt[c][j] layout.
    {
        char* zl = (char*)&zt[0][0];
#pragma unroll
        for (int i = 0; i < 8; ++i) {
            const int c0 = wv * 64 + i * 8;
            GLOAD_LDS16(zg + (size_t)(c0 + (lane >> 3)) * 4096 + (lane & 7) * 16,
                        zl + (size_t)c0 * 128);
        }
    }
    // ---- pmeta load overlaps the DMA flight (drained by the same vmcnt)
    u64 mym = 0;
    if (t < 32) mym = pmeta[row0 + t];
    if (t == 0) { pcount = 0; fcount = 0; }
    asm volatile("s_waitcnt vmcnt(0)" ::: "memory");
    __syncthreads();  // zt complete, counters zeroed

    // ---- decode pmeta
    if (t < 32) {
        const u64 m = mym;
        if (m & RESOLVED) {
            kidx[t] = (int)(m & 1023u);
        } else if ((m >> 16) & 1ull) {
            const int s = atomicAdd(&fcount, 1);
            frow[s] = t;
        } else {
            const int s = atomicAdd(&pcount, 1);
            prow[s] = t;
            pm[s] = m;
        }
    }
    __syncthreads();

    // ---- candidate rows (n<=3): 16 groups of 16 threads.
    {
        const int g = t >> 4;
        const int j = t & 15;
        const int wbase = (t & 63) - j;
        const int np = pcount;
        for (int p = g; p < np; p += 16) {
            const int row = prow[p];
            const u64 m = pm[p];
            const unsigned cc[3] = {(unsigned)((m >> 17) & 1023u),
                                    (unsigned)((m >> 27) & 1023u),
                                    (unsigned)((m >> 37) & 1023u)};
            float ch;
            {
#pragma clang fp contract(off)
                const int half = j >> 3;
                const int j0 = j & 7;
                float v = zt[half * 128 + j0][row];
                ch = v * v;
                for (int i = 1; i < 16; ++i) {
                    float u = zt[half * 128 + 8 * i + j0][row];
                    ch += u * u;
                }
            }
            float aval;
            {
#pragma clang fp contract(off)
                float r0 = __shfl(ch, wbase + 0), r1 = __shfl(ch, wbase + 1),
                      r2 = __shfl(ch, wbase + 2), r3 = __shfl(ch, wbase + 3),
                      r4 = __shfl(ch, wbase + 4), r5 = __shfl(ch, wbase + 5),
                      r6 = __shfl(ch, wbase + 6), r7 = __shfl(ch, wbase + 7),
                      r8 = __shfl(ch, wbase + 8), r9 = __shfl(ch, wbase + 9),
                      ra = __shfl(ch, wbase + 10), rb = __shfl(ch, wbase + 11),
                      rc = __shfl(ch, wbase + 12), rd = __shfl(ch, wbase + 13),
                      re = __shfl(ch, wbase + 14), rf = __shfl(ch, wbase + 15);
                float lo = ((r0 + r1) + (r2 + r3)) + ((r4 + r5) + (r6 + r7));
                float hi = ((r8 + r9) + (ra + rb)) + ((rc + rd) + (re + rf));
                aval = lo + hi;
            }

            float bd = 3.0e38f;
            int bk = 0x7fffffff;
            if (j < 3 && cc[j] < 512u) {
                const int k = (int)cc[j];
                const float* ep = cb + (size_t)k * D;
                float a = 0.f;
#pragma unroll 8
                for (int c = 0; c < D; ++c) a = fmaf(zt[c][row], ep[c], a);
                {
#pragma clang fp contract(off)
                    float t1 = aval + Bv[k];
                    bd = t1 - 2.0f * a;
                }
                bk = k;
            }
#pragma unroll
            for (int s = 1; s < 16; s <<= 1) {
                float od = __shfl_xor(bd, s);
                int ok = __shfl_xor(bk, s);
                if (od < bd || (od == bd && ok < bk)) { bd = od; bk = ok; }
            }
            if (j == 0) kidx[row] = bk;
        }
    }
    __syncthreads();

    // ---- full rows: block-cooperative, 2 interleaved chains per thread.
    {
        const int nf = fcount;
        for (int p = 0; p < nf; ++p) {
            const int row = frow[p];
            if (wv == 0) {
                const int j = lane & 15;
                float ch;
                {
#pragma clang fp contract(off)
                    const int half = j >> 3;
                    const int j0 = j & 7;
                    float v = zt[half * 128 + j0][row];
                    ch = v * v;
                    for (int i = 1; i < 16; ++i) {
                        float u = zt[half * 128 + 8 * i + j0][row];
                        ch += u * u;
                    }
                }
                {
#pragma clang fp contract(off)
                    float r0 = __shfl(ch, 0), r1 = __shfl(ch, 1),
                          r2 = __shfl(ch, 2), r3 = __shfl(ch, 3),
                          r4 = __shfl(ch, 4), r5 = __shfl(ch, 5),
                          r6 = __shfl(ch, 6), r7 = __shfl(ch, 7),
                          r8 = __shfl(ch, 8), r9 = __shfl(ch, 9),
                          ra = __shfl(ch, 10), rb = __shfl(ch, 11),
                          rc = __shfl(ch, 12), rd = __shfl(ch, 13),
                          re = __shfl(ch, 14), rf = __shfl(ch, 15);
                    float lo = ((r0 + r1) + (r2 + r3)) + ((r4 + r5) + (r6 + r7));
                    float hi = ((r8 + r9) + (ra + rb)) + ((rc + rd) + (re + rf));
                    if (lane == 0) faval = lo + hi;
                }
            }
            __syncthreads();

            const float aval = faval;
            const int k0 = t;
            const int k1 = t + 256;
            const float* e0 = cb + (size_t)k0 * D;
            const float* e1 = cb + (size_t)k1 * D;
            float a0 = 0.f, a1 = 0.f;
#pragma unroll 8
            for (int c = 0; c < D; ++c) {
                const float z = zt[c][row];
                a0 = fmaf(z, e0[c], a0);
                a1 = fmaf(z, e1[c], a1);
            }
            float dv0, dv1;
            {
#pragma clang fp contract(off)
                float t0v = aval + Bv[k0];
                dv0 = t0v - 2.0f * a0;
                float t1v = aval + Bv[k1];
                dv1 = t1v - 2.0f * a1;
            }
            float bd = dv0;
            int bk = k0;
            if (dv1 < bd) { bd = dv1; bk = k1; }  // k0 < k1: tie keeps k0
#pragma unroll
            for (int s = 1; s < 64; s <<= 1) {
                float od = __shfl_xor(bd, s);
                int ok = __shfl_xor(bk, s);
                if (od < bd || (od == bd && ok < bk)) { bd = od; bk = ok; }
            }
            if (lane == 0) { fbd[wv] = bd; fbk[wv] = bk; }
            __syncthreads();
            if (t == 0) {
                float xbd = fbd[0];
                int xbk = fbk[0];
#pragma unroll
                for (int q = 1; q < 4; ++q) {
                    if (fbd[q] < xbd || (fbd[q] == xbd && fbk[q] < xbk)) {
                        xbd = fbd[q];
                        xbk = fbk[q];
                    }
                }
                kidx[row] = xbk;
            }
            __syncthreads();
        }
    }
    __syncthreads();

    // ---- gather / ST write / index output / loss partial (z from LDS)
    if (t < 32) out[IDX_OFF + row0 + t] = (float)kidx[t];
    {
        const int j = t & 31;       // row
        const int cq = t >> 5;      // channel group (32 channels)
        const int kme = kidx[j];
        const float* ep = cb + (size_t)kme * D;
        float* ob = out + (size_t)b * CHW + hw0 + j;
        float accum = 0.f;
#pragma unroll 4
        for (int i = 0; i < 32; ++i) {
            const int c = cq * 32 + i;
            const float z = zt[c][j];
            const float e = ep[c];
            ob[(size_t)c * HW] = z + (e - z);
            const float df = z - e;
            accum = fmaf(df, df, accum);
        }
#pragma unroll
        for (int s = 1; s < 64; s <<= 1) accum += __shfl_xor(accum, s);
        if (lane == 0) wpart[wv] = accum;
    }
    __syncthreads();
    if (t == 0) part[blk] = (wpart[0] + wpart[1]) + (wpart[2] + wpart[3]);
}

// ---------------------------------------------------------------------------
// Kernel 4: final loss reduction (2048 partials, fp64, deterministic).
__global__ void vq_finish(const float* __restrict__ part, float* __restrict__ out) {
    const int t = threadIdx.x;
    double s = 0.0;
#pragma unroll
    for (int i = 0; i < 8; ++i) s += (double)part[t + 256 * i];
#pragma unroll
    for (int m = 1; m < 64; m <<= 1) s += __shfl_xor(s, m);
    __shared__ double wsum[4];
    if ((t & 63) == 0) wsum[t >> 6] = s;
    __syncthreads();
    if (t == 0) {
        double mean = (wsum[0] + wsum[1] + wsum[2] + wsum[3]) / (double)ZQ_SIZE;
        out[LOSS0_OFF] = (float)mean;
        out[LOSS1_OFF] = (float)mean;
    }
}

// ---------------------------------------------------------------------------
extern "C" void kernel_launch(void* const* d_in, const int* in_sizes, int n_in,
                              void* d_out, int out_size, void* d_ws, size_t ws_size,
                              hipStream_t stream) {
    const float* z_e = (const float*)d_in[0];
    const float* cb = (const float*)d_in[1];
    float* out = (float*)d_out;
    float* ws = (float*)d_ws;

    const ushort_t* ehb = (const ushort_t*)ws;
    float* Bv = ws + WS_B;
    float* part = ws + WS_PART;
    u64* pmeta = (u64*)(ws + WS_PMETA);

    vq_prep<<<K, D, 0, stream>>>(cb, ws);
    vq_argmin7<<<NBLK_A, 64, 0, stream>>>(z_e, ehb, Bv, pmeta);
    vq_gather3<<<NBLK_G, 256, 0, stream>>>(z_e, cb, Bv, pmeta, part, out);
    vq_finish<<<1, 256, 0, stream>>>(part, out);
}